// Round 1
// baseline (2861.693 us; speedup 1.0000x reference)
//
#include <hip/hip_runtime.h>

// Problem constants: B=2, C=96, D=H=W=40, S=64000, NH=4, HD=24, L=40
// Exact simplifications vs reference:
//  - pos_attn branch dropped (softmax row-shift invariance)
//  - R6 rotations dropped (R orthogonal; (Rq).(Rk) = q.k; v unrotated)

// ---------------- weight transposes (tiny) ----------------
__global__ void k_transpose_w1(const float* __restrict__ w, float* __restrict__ wt) {
    int i = blockIdx.x * 256 + threadIdx.x;
    if (i < 27 * 96 * 96) {
        int o = i % 96, c = (i / 96) % 96, tap = i / (96 * 96);
        wt[i] = w[(o * 96 + c) * 27 + tap];   // wt[tap][c][o]
    }
}

__global__ void k_transpose_qkvw(const float* __restrict__ w, float* __restrict__ wt) {
    int i = blockIdx.x * 256 + threadIdx.x;
    if (i < 288 * 96) {
        int m = i % 288, c = i / 288;
        wt[i] = w[m * 96 + c];                // wt[c][m]
    }
}

// ---------------- conv 3x3x3 circular ----------------
// block = 192 threads: o-pair = (t%48)*2, w-tile of 10 = (t/48)*10
// LDS: input c-chunk of 32, 9 (kd,kh) halo rows, 42 circular-w values (pad 44)
__global__ __launch_bounds__(192) void k_conv3(const float* __restrict__ in,
                                               const float* __restrict__ wt,   // [tap][c][o]
                                               const float* __restrict__ bias,
                                               float* __restrict__ out) {
    __shared__ float tile[32][9][44];
    int bid = blockIdx.x;
    int b = bid / 1600, r = bid % 1600;
    int d0 = r / 40, h0 = r % 40;
    int t = threadIdx.x;
    int o0 = (t % 48) * 2, w0 = (t / 48) * 10;
    float acc[2][10];
#pragma unroll
    for (int a = 0; a < 2; a++)
#pragma unroll
        for (int j = 0; j < 10; j++) acc[a][j] = 0.f;

    for (int cc = 0; cc < 3; cc++) {
        if (cc) __syncthreads();
        for (int i = t; i < 32 * 9 * 42; i += 192) {
            int wp = i % 42, row = (i / 42) % 9, c = i / 378;
            int kd = row / 3, kh = row % 3;
            int ds = d0 + kd - 1; if (ds < 0) ds += 40; if (ds >= 40) ds -= 40;
            int hs = h0 + kh - 1; if (hs < 0) hs += 40; if (hs >= 40) hs -= 40;
            int wsrc = wp - 1; if (wsrc < 0) wsrc += 40; if (wsrc >= 40) wsrc -= 40;
            tile[c][row][wp] = in[(((b * 96 + cc * 32 + c) * 40 + ds) * 40 + hs) * 40 + wsrc];
        }
        __syncthreads();
        for (int c = 0; c < 32; c++) {
            int cg = cc * 32 + c;
#pragma unroll
            for (int row = 0; row < 9; row++) {
                const float2* rp = (const float2*)&tile[c][row][w0];
                float rv[12];
#pragma unroll
                for (int q = 0; q < 6; q++) { float2 v = rp[q]; rv[2 * q] = v.x; rv[2 * q + 1] = v.y; }
#pragma unroll
                for (int kw = 0; kw < 3; kw++) {
                    float2 wv = *(const float2*)&wt[((row * 3 + kw) * 96 + cg) * 96 + o0];
#pragma unroll
                    for (int j = 0; j < 10; j++) {
                        acc[0][j] += wv.x * rv[j + kw];
                        acc[1][j] += wv.y * rv[j + kw];
                    }
                }
            }
        }
    }
#pragma unroll
    for (int a = 0; a < 2; a++) {
        float bb = bias[o0 + a];
        float* op = &out[(((b * 96 + o0 + a) * 40 + d0) * 40 + h0) * 40 + w0];
#pragma unroll
        for (int j = 0; j < 10; j++) op[j] = acc[a][j] + bb;
    }
}

// ---------------- instance-norm stats (per (b,c) over 64000) ----------------
__global__ __launch_bounds__(256) void k_stats(const float* __restrict__ in, float2* __restrict__ stats) {
    int bc = blockIdx.x;
    const float4* p = (const float4*)(in + (size_t)bc * 64000);
    int t = threadIdx.x;
    float s = 0.f, sq = 0.f;
    for (int i = t; i < 16000; i += 256) {
        float4 v = p[i];
        s += v.x + v.y + v.z + v.w;
        sq += v.x * v.x + v.y * v.y + v.z * v.z + v.w * v.w;
    }
    __shared__ float rs[256], rq[256];
    rs[t] = s; rq[t] = sq;
    __syncthreads();
    for (int off = 128; off > 0; off >>= 1) {
        if (t < off) { rs[t] += rs[t + off]; rq[t] += rq[t + off]; }
        __syncthreads();
    }
    if (t == 0) {
        float mu = rs[0] * (1.f / 64000.f);
        float var = rq[0] * (1.f / 64000.f) - mu * mu;
        stats[bc] = make_float2(mu, rsqrtf(var + 1e-5f));
    }
}

// ---------------- (x-mu)*rstd then exact gelu, in-place ----------------
__global__ __launch_bounds__(256) void k_norm_gelu(float* __restrict__ x, const float2* __restrict__ stats) {
    int i = blockIdx.x * 256 + threadIdx.x;   // float4 index, 3,072,000 total
    int bc = i / 16000;
    float2 st = stats[bc];
    float4 v = ((const float4*)x)[i];
    float* f = &v.x;
#pragma unroll
    for (int q = 0; q < 4; q++) {
        float u = (f[q] - st.x) * st.y;
        f[q] = 0.5f * u * (1.f + erff(u * 0.70710678118654752f));
    }
    ((float4*)x)[i] = v;
}

// ---------------- x * mod ----------------
__global__ __launch_bounds__(256) void k_xmod(const float4* __restrict__ x, const float4* __restrict__ m,
                                              float4* __restrict__ out) {
    int i = blockIdx.x * 256 + threadIdx.x;
    float4 a = x[i], b = m[i];
    out[i] = make_float4(a.x * b.x, a.y * b.y, a.z * b.z, a.w * b.w);
}

// ---------------- 1x1 conv (96x96 channel GEMM), MODE 0=bias, 1=bias+sigmoid ----------------
template <int MODE>
__global__ __launch_bounds__(256) void k_conv1x1(const float* __restrict__ in,
                                                 const float* __restrict__ w,
                                                 const float* __restrict__ bias,
                                                 float* __restrict__ out) {
    __shared__ float wl[96][98];   // [c][o]
    __shared__ float it[96][64];   // [c][s]
    int bid = blockIdx.x;
    int b = bid / 1000;
    int s0 = (bid % 1000) * 64;
    int t = threadIdx.x;
    for (int i = t; i < 96 * 96; i += 256) wl[i % 96][i / 96] = w[i];
    for (int i = t; i < 96 * 64; i += 256) {
        int c = i / 64, sl = i % 64;
        it[c][sl] = in[(b * 96 + c) * 64000 + s0 + sl];
    }
    __syncthreads();
    int og = t / 16, sg = t % 16;   // 6 o's, 4 s's per thread
    float acc[6][4];
#pragma unroll
    for (int j = 0; j < 6; j++)
#pragma unroll
        for (int q = 0; q < 4; q++) acc[j][q] = 0.f;
    for (int c = 0; c < 96; c++) {
        float4 v = *(const float4*)&it[c][sg * 4];
#pragma unroll
        for (int j = 0; j < 6; j++) {
            float wv = wl[c][og * 6 + j];
            acc[j][0] += wv * v.x; acc[j][1] += wv * v.y; acc[j][2] += wv * v.z; acc[j][3] += wv * v.w;
        }
    }
#pragma unroll
    for (int j = 0; j < 6; j++) {
        int o = og * 6 + j;
        float bb = bias[o];
        float4 rr;
        rr.x = acc[j][0] + bb; rr.y = acc[j][1] + bb; rr.z = acc[j][2] + bb; rr.w = acc[j][3] + bb;
        if (MODE == 1) {
            rr.x = 1.f / (1.f + expf(-rr.x)); rr.y = 1.f / (1.f + expf(-rr.y));
            rr.z = 1.f / (1.f + expf(-rr.z)); rr.w = 1.f / (1.f + expf(-rr.w));
        }
        *(float4*)&out[(b * 96 + o) * 64000 + s0 + sg * 4] = rr;
    }
}

// ---------------- fused axial attention (qkv + scores + softmax + PV) ----------------
// One block per (b, line). L=40, C=96, NH=4, HD=24. scale = 24^-0.5.
// Phase 1 (240 threads): qkv GEMM, reg tile 4 l x 12 m, weights streamed from global (coalesced).
// Phase 2 (80 threads): per (head, ql-pair): scores vs kT rows, softmax, PV vs vT rows.
template <int AXIS, bool ACC>
__global__ __launch_bounds__(256) void k_attn(const float* __restrict__ xm,
                                              const float* __restrict__ qwt,  // [c][288]
                                              const float* __restrict__ qb,
                                              float* __restrict__ out) {
    __shared__ float xl[96 * 40];     // [c][l]
    __shared__ float qs[40][100];     // q: [l][m]
    __shared__ float kT[96][44];      // k: [m][l]
    __shared__ float vT[96][44];      // v: [m][l]
    int bid = blockIdx.x;
    int b = bid / 1600, r = bid % 1600;
    int offset, stride;
    if (AXIS == 0) { stride = 1600; offset = r; }                         // line along d; (h,w)=r
    else if (AXIS == 1) { stride = 40; offset = (r / 40) * 1600 + (r % 40); } // line along h; (d,w)
    else { stride = 1; offset = r * 40; }                                 // line along w; (d,h)
    int t = threadIdx.x;
    const float* base = xm + b * 96 * 64000 + offset;
    for (int i = t; i < 96 * 40; i += 256) {
        int c = i / 40, l = i % 40;
        xl[c * 40 + l] = base[c * 64000 + l * stride];
    }
    __syncthreads();

    if (t < 240) {
        int lg = t / 24, mg = t % 24;
        int l0 = lg * 4, m0 = mg * 12;
        float acc[4][12];
#pragma unroll
        for (int l = 0; l < 4; l++)
#pragma unroll
            for (int j = 0; j < 12; j++) acc[l][j] = 0.f;
        for (int c = 0; c < 96; c++) {
            float4 xv = *(const float4*)&xl[c * 40 + l0];
            const float4* wp = (const float4*)&qwt[c * 288 + m0];
            float4 w0 = wp[0], w1 = wp[1], w2 = wp[2];
            const float* wf = &w0.x;   // w0..w2 contiguous? not guaranteed; use explicit
            float wv[12] = {w0.x, w0.y, w0.z, w0.w, w1.x, w1.y, w1.z, w1.w, w2.x, w2.y, w2.z, w2.w};
            float xf[4] = {xv.x, xv.y, xv.z, xv.w};
            (void)wf;
#pragma unroll
            for (int l = 0; l < 4; l++)
#pragma unroll
                for (int j = 0; j < 12; j++) acc[l][j] += xf[l] * wv[j];
        }
        float br[12];
#pragma unroll
        for (int j = 0; j < 12; j++) br[j] = qb[m0 + j];
#pragma unroll
        for (int l = 0; l < 4; l++) {
            int ll = l0 + l;
#pragma unroll
            for (int j = 0; j < 12; j++) {
                int m = m0 + j;
                float v = acc[l][j] + br[j];
                if (m < 96) qs[ll][m] = v;
                else if (m < 192) kT[m - 96][ll] = v;
                else vT[m - 192][ll] = v;
            }
        }
    }
    __syncthreads();

    if (t < 80) {
        int h = t / 20, qlp = t % 20;
        int ql0 = qlp * 2, ql1 = ql0 + 1;
        float s0r[40], s1r[40];
#pragma unroll
        for (int i = 0; i < 40; i++) { s0r[i] = 0.f; s1r[i] = 0.f; }
        for (int hd = 0; hd < 24; hd++) {
            float q0 = qs[ql0][h * 24 + hd];
            float q1 = qs[ql1][h * 24 + hd];
            const float4* kp = (const float4*)&kT[h * 24 + hd][0];
#pragma unroll
            for (int q4 = 0; q4 < 10; q4++) {
                float4 kv = kp[q4];
                s0r[4 * q4 + 0] += q0 * kv.x; s0r[4 * q4 + 1] += q0 * kv.y;
                s0r[4 * q4 + 2] += q0 * kv.z; s0r[4 * q4 + 3] += q0 * kv.w;
                s1r[4 * q4 + 0] += q1 * kv.x; s1r[4 * q4 + 1] += q1 * kv.y;
                s1r[4 * q4 + 2] += q1 * kv.z; s1r[4 * q4 + 3] += q1 * kv.w;
            }
        }
        const float scale = 0.20412414523193154f;
        float m0 = -1e30f, m1 = -1e30f;
#pragma unroll
        for (int i = 0; i < 40; i++) {
            s0r[i] *= scale; s1r[i] *= scale;
            m0 = fmaxf(m0, s0r[i]); m1 = fmaxf(m1, s1r[i]);
        }
        float sum0 = 0.f, sum1 = 0.f;
#pragma unroll
        for (int i = 0; i < 40; i++) {
            s0r[i] = expf(s0r[i] - m0); sum0 += s0r[i];
            s1r[i] = expf(s1r[i] - m1); sum1 += s1r[i];
        }
        float inv0 = 1.f / sum0, inv1 = 1.f / sum1;
        for (int hd = 0; hd < 24; hd++) {
            const float4* vp = (const float4*)&vT[h * 24 + hd][0];
            float o0 = 0.f, o1 = 0.f;
#pragma unroll
            for (int q4 = 0; q4 < 10; q4++) {
                float4 vv = vp[q4];
                o0 += s0r[4 * q4 + 0] * vv.x + s0r[4 * q4 + 1] * vv.y + s0r[4 * q4 + 2] * vv.z + s0r[4 * q4 + 3] * vv.w;
                o1 += s1r[4 * q4 + 0] * vv.x + s1r[4 * q4 + 1] * vv.y + s1r[4 * q4 + 2] * vv.z + s1r[4 * q4 + 3] * vv.w;
            }
            o0 *= inv0; o1 *= inv1;
            int cbase = (b * 96 + h * 24 + hd) * 64000 + offset;
            if (ACC) {
                out[cbase + ql0 * stride] += o0;
                out[cbase + ql1 * stride] += o1;
            } else {
                out[cbase + ql0 * stride] = o0;
                out[cbase + ql1 * stride] = o1;
            }
        }
    }
}

extern "C" void kernel_launch(void* const* d_in, const int* in_sizes, int n_in,
                              void* d_out, int out_size, void* d_ws, size_t ws_size,
                              hipStream_t stream) {
    const float* x      = (const float*)d_in[0];
    const float* pos    = (const float*)d_in[1];
    const float* qkv_w  = (const float*)d_in[2];
    const float* qkv_b  = (const float*)d_in[3];
    const float* lp1_w  = (const float*)d_in[4];
    const float* lp1_b  = (const float*)d_in[5];
    const float* lp2_w  = (const float*)d_in[6];
    const float* lp2_b  = (const float*)d_in[7];
    const float* mod1_w = (const float*)d_in[8];
    const float* mod1_b = (const float*)d_in[9];
    const float* mod2_w = (const float*)d_in[10];
    const float* mod2_b = (const float*)d_in[11];
    // d_in[12..16]: pa_w, pa_b, R6_d, R6_h, R6_w — provably no-ops (see header)
    const float* proj_w = (const float*)d_in[17];
    const float* proj_b = (const float*)d_in[18];
    float* out = (float*)d_out;
    float* ws = (float*)d_ws;

    float* buf0 = ws;                       // 12,288,000 floats
    float* buf1 = ws + 12288000;            // 12,288,000 floats
    float2* stats = (float2*)(ws + 24576000);  // 192 float2
    float* w1t = ws + 24576384;             // 248,832 floats  [tap][c][o]
    float* qwt = w1t + 248832;              // 27,648 floats   [c][m]

    k_transpose_w1<<<972, 256, 0, stream>>>(lp1_w, w1t);
    k_transpose_qkvw<<<108, 256, 0, stream>>>(qkv_w, qwt);

    // local = conv1x1(gelu(IN(conv3(pos))))
    k_conv3<<<3200, 192, 0, stream>>>(pos, w1t, lp1_b, buf0);
    k_stats<<<192, 256, 0, stream>>>(buf0, stats);
    k_norm_gelu<<<12000, 256, 0, stream>>>(buf0, stats);
    k_conv1x1<0><<<2000, 256, 0, stream>>>(buf0, lp2_w, lp2_b, buf1);

    // mod = sigmoid(conv1x1(gelu(IN(conv1x1(local)))))
    k_conv1x1<0><<<2000, 256, 0, stream>>>(buf1, mod1_w, mod1_b, buf0);
    k_stats<<<192, 256, 0, stream>>>(buf0, stats);
    k_norm_gelu<<<12000, 256, 0, stream>>>(buf0, stats);
    k_conv1x1<1><<<2000, 256, 0, stream>>>(buf0, mod2_w, mod2_b, buf1);

    // x_mod = x * mod
    k_xmod<<<12000, 256, 0, stream>>>((const float4*)x, (const float4*)buf1, (float4*)buf0);

    // axial attention: axis d writes, axes h/w accumulate
    k_attn<0, false><<<3200, 256, 0, stream>>>(buf0, qwt, qkv_b, buf1);
    k_attn<1, true ><<<3200, 256, 0, stream>>>(buf0, qwt, qkv_b, buf1);
    k_attn<2, true ><<<3200, 256, 0, stream>>>(buf0, qwt, qkv_b, buf1);

    // out = conv1x1(out_sum, proj)
    k_conv1x1<0><<<2000, 256, 0, stream>>>(buf1, proj_w, proj_b, out);
}

// Round 2
// 1568.861 us; speedup vs baseline: 1.8241x; 1.8241x over previous
//
#include <hip/hip_runtime.h>

// Problem constants: B=2, C=96, D=H=W=40, S=64000, NH=4, HD=24, L=40
// Exact simplifications vs reference:
//  - pos_attn branch dropped (softmax row-shift invariance)
//  - R6 rotations dropped (R orthogonal; (Rq).(Rk) = q.k; v unrotated)
// Round 2: conv3 rewritten as bf16 MFMA implicit GEMM (M=96 o, N=128000 spatial,
// K=2592 = 27 taps x 96 c). Inputs pre-transposed: in_t bf16 [b][s][c],
// weights wb2 bf16 [tap][o][c].

typedef __attribute__((ext_vector_type(8))) short short8;
typedef __attribute__((ext_vector_type(16))) float floatx16;

static __device__ __forceinline__ unsigned short f2bf(float f) {
    unsigned int u = __builtin_bit_cast(unsigned int, f);
    u = u + 0x7FFFu + ((u >> 16) & 1u);   // RNE
    return (unsigned short)(u >> 16);
}

// ---------------- prep: pos fp32 [b][c][s] -> bf16 [b][s][c] ----------------
__global__ __launch_bounds__(256) void k_cvt_in(const float* __restrict__ pos,
                                                unsigned short* __restrict__ in_t) {
    __shared__ unsigned short lds[64][97];
    int bid = blockIdx.x;
    int b = bid / 1000, s0 = (bid % 1000) * 64;
    int t = threadIdx.x;
    for (int i = t; i < 6144; i += 256) {
        int c = i / 64, sl = i % 64;
        lds[sl][c] = f2bf(pos[(b * 96 + c) * 64000 + s0 + sl]);
    }
    __syncthreads();
    unsigned short* outp = in_t + ((size_t)b * 64000 + s0) * 96;
    for (int i = t; i < 6144; i += 256) {
        int sl = i / 96, c = i % 96;
        outp[i] = lds[sl][c];
    }
}

// ---------------- prep: lp1_w [o][c][tap] -> bf16 wb2 [tap][o][c] ----------------
__global__ void k_cvt_w(const float* __restrict__ w, unsigned short* __restrict__ wb2) {
    int i = blockIdx.x * 256 + threadIdx.x;
    if (i < 248832) {
        int c = i % 96, m = (i / 96) % 96, tap = i / 9216;
        wb2[i] = f2bf(w[(m * 96 + c) * 27 + tap]);
    }
}

__global__ void k_transpose_qkvw(const float* __restrict__ w, float* __restrict__ wt) {
    int i = blockIdx.x * 256 + threadIdx.x;
    if (i < 288 * 96) {
        int m = i % 288, c = i / 288;
        wt[i] = w[m * 96 + c];                // wt[c][m]
    }
}

// ---------------- conv 3x3x3 circular as MFMA implicit GEMM ----------------
// Block: 256 threads (4 waves), output tile M=96 x N=256 spatial positions.
// Wave w: all 3 M-tiles(32) x 2 N-tiles(32) at n = w*64.
// K-loop: 27 taps x 6 c-chunks(16). A (weights) per-tap in LDS; B (input)
// fragments gathered from global bf16 [s][c] via per-block shift table.
__global__ __launch_bounds__(256) void k_conv3_mfma(const unsigned short* __restrict__ in_t,
                                                    const unsigned short* __restrict__ wb2,
                                                    const float* __restrict__ bias,
                                                    float* __restrict__ out) {
    __shared__ unsigned short A_lds[96 * 104];   // row stride 208 B (96 c + 8 pad)
    __shared__ int tbl[27 * 256];
    __shared__ float bsh[96];
    int t = threadIdx.x;
    int bid = blockIdx.x;
    int b = bid / 250;
    int s0 = (bid % 250) * 256;

    for (int u = t; u < 27 * 256; u += 256) {
        int tap = u >> 8, nl = u & 255;
        int kd = tap / 9, kh = (tap / 3) % 3, kw = tap % 3;
        int s = s0 + nl;
        int d = s / 1600, r = s - d * 1600;
        int h = r / 40, w = r - h * 40;
        int ds = d + kd - 1; if (ds < 0) ds += 40; else if (ds >= 40) ds -= 40;
        int hs = h + kh - 1; if (hs < 0) hs += 40; else if (hs >= 40) hs -= 40;
        int wv2 = w + kw - 1; if (wv2 < 0) wv2 += 40; else if (wv2 >= 40) wv2 -= 40;
        tbl[u] = ((ds * 1600 + hs * 40 + wv2) * 96) * 2;   // byte offset in batch slab
    }
    if (t < 96) bsh[t] = bias[t];

    int wv = t >> 6;
    int lane = t & 63;
    int n31 = lane & 31;
    int kg = lane >> 5;

    const char* inb = (const char*)(in_t + (size_t)b * 64000 * 96) + kg * 16;

    floatx16 acc[3][2];
#pragma unroll
    for (int mt = 0; mt < 3; mt++)
#pragma unroll
        for (int nt = 0; nt < 2; nt++)
#pragma unroll
            for (int r = 0; r < 16; r++) acc[mt][nt][r] = 0.f;

    for (int tap = 0; tap < 27; tap++) {
        __syncthreads();
        const uint4* wsrc = (const uint4*)(wb2 + tap * 9216);
        for (int u = t; u < 1152; u += 256) {
            int m = u / 12, seg = u % 12;
            uint4 v = wsrc[u];
            *(uint4*)((char*)A_lds + m * 208 + seg * 16) = v;
        }
        __syncthreads();
        int ta0 = tbl[tap * 256 + wv * 64 + n31];
        int ta1 = tbl[tap * 256 + wv * 64 + 32 + n31];
        const char* pb0 = inb + ta0;
        const char* pb1 = inb + ta1;
#pragma unroll
        for (int j = 0; j < 6; j++) {
            short8 a0 = *(short8*)((char*)A_lds + (n31) * 208 + j * 32 + kg * 16);
            short8 a1 = *(short8*)((char*)A_lds + (32 + n31) * 208 + j * 32 + kg * 16);
            short8 a2 = *(short8*)((char*)A_lds + (64 + n31) * 208 + j * 32 + kg * 16);
            short8 b0 = *(const short8*)(pb0 + j * 32);
            short8 b1 = *(const short8*)(pb1 + j * 32);
            acc[0][0] = __builtin_amdgcn_mfma_f32_32x32x16_bf16(a0, b0, acc[0][0], 0, 0, 0);
            acc[0][1] = __builtin_amdgcn_mfma_f32_32x32x16_bf16(a0, b1, acc[0][1], 0, 0, 0);
            acc[1][0] = __builtin_amdgcn_mfma_f32_32x32x16_bf16(a1, b0, acc[1][0], 0, 0, 0);
            acc[1][1] = __builtin_amdgcn_mfma_f32_32x32x16_bf16(a1, b1, acc[1][1], 0, 0, 0);
            acc[2][0] = __builtin_amdgcn_mfma_f32_32x32x16_bf16(a2, b0, acc[2][0], 0, 0, 0);
            acc[2][1] = __builtin_amdgcn_mfma_f32_32x32x16_bf16(a2, b1, acc[2][1], 0, 0, 0);
        }
    }

    int sbase = s0 + wv * 64;
#pragma unroll
    for (int mt = 0; mt < 3; mt++)
#pragma unroll
        for (int nt = 0; nt < 2; nt++)
#pragma unroll
            for (int r = 0; r < 16; r++) {
                int o = mt * 32 + (r & 3) + 8 * (r >> 2) + 4 * kg;
                int s = sbase + nt * 32 + n31;
                out[(b * 96 + o) * 64000 + s] = acc[mt][nt][r] + bsh[o];
            }
}

// ---------------- instance-norm stats (per (b,c) over 64000) ----------------
__global__ __launch_bounds__(256) void k_stats(const float* __restrict__ in, float2* __restrict__ stats) {
    int bc = blockIdx.x;
    const float4* p = (const float4*)(in + (size_t)bc * 64000);
    int t = threadIdx.x;
    float s = 0.f, sq = 0.f;
    for (int i = t; i < 16000; i += 256) {
        float4 v = p[i];
        s += v.x + v.y + v.z + v.w;
        sq += v.x * v.x + v.y * v.y + v.z * v.z + v.w * v.w;
    }
    __shared__ float rs[256], rq[256];
    rs[t] = s; rq[t] = sq;
    __syncthreads();
    for (int off = 128; off > 0; off >>= 1) {
        if (t < off) { rs[t] += rs[t + off]; rq[t] += rq[t + off]; }
        __syncthreads();
    }
    if (t == 0) {
        float mu = rs[0] * (1.f / 64000.f);
        float var = rq[0] * (1.f / 64000.f) - mu * mu;
        stats[bc] = make_float2(mu, rsqrtf(var + 1e-5f));
    }
}

// ---------------- (x-mu)*rstd then exact gelu, in-place ----------------
__global__ __launch_bounds__(256) void k_norm_gelu(float* __restrict__ x, const float2* __restrict__ stats) {
    int i = blockIdx.x * 256 + threadIdx.x;   // float4 index, 3,072,000 total
    int bc = i / 16000;
    float2 st = stats[bc];
    float4 v = ((const float4*)x)[i];
    float* f = &v.x;
#pragma unroll
    for (int q = 0; q < 4; q++) {
        float u = (f[q] - st.x) * st.y;
        f[q] = 0.5f * u * (1.f + erff(u * 0.70710678118654752f));
    }
    ((float4*)x)[i] = v;
}

// ---------------- x * mod ----------------
__global__ __launch_bounds__(256) void k_xmod(const float4* __restrict__ x, const float4* __restrict__ m,
                                              float4* __restrict__ out) {
    int i = blockIdx.x * 256 + threadIdx.x;
    float4 a = x[i], b = m[i];
    out[i] = make_float4(a.x * b.x, a.y * b.y, a.z * b.z, a.w * b.w);
}

// ---------------- 1x1 conv (96x96 channel GEMM), MODE 0=bias, 1=bias+sigmoid ----------------
template <int MODE>
__global__ __launch_bounds__(256) void k_conv1x1(const float* __restrict__ in,
                                                 const float* __restrict__ w,
                                                 const float* __restrict__ bias,
                                                 float* __restrict__ out) {
    __shared__ float wl[96][98];   // [c][o]
    __shared__ float it[96][64];   // [c][s]
    int bid = blockIdx.x;
    int b = bid / 1000;
    int s0 = (bid % 1000) * 64;
    int t = threadIdx.x;
    for (int i = t; i < 96 * 96; i += 256) wl[i % 96][i / 96] = w[i];
    for (int i = t; i < 96 * 64; i += 256) {
        int c = i / 64, sl = i % 64;
        it[c][sl] = in[(b * 96 + c) * 64000 + s0 + sl];
    }
    __syncthreads();
    int og = t / 16, sg = t % 16;   // 6 o's, 4 s's per thread
    float acc[6][4];
#pragma unroll
    for (int j = 0; j < 6; j++)
#pragma unroll
        for (int q = 0; q < 4; q++) acc[j][q] = 0.f;
    for (int c = 0; c < 96; c++) {
        float4 v = *(const float4*)&it[c][sg * 4];
#pragma unroll
        for (int j = 0; j < 6; j++) {
            float wv = wl[c][og * 6 + j];
            acc[j][0] += wv * v.x; acc[j][1] += wv * v.y; acc[j][2] += wv * v.z; acc[j][3] += wv * v.w;
        }
    }
#pragma unroll
    for (int j = 0; j < 6; j++) {
        int o = og * 6 + j;
        float bb = bias[o];
        float4 rr;
        rr.x = acc[j][0] + bb; rr.y = acc[j][1] + bb; rr.z = acc[j][2] + bb; rr.w = acc[j][3] + bb;
        if (MODE == 1) {
            rr.x = 1.f / (1.f + expf(-rr.x)); rr.y = 1.f / (1.f + expf(-rr.y));
            rr.z = 1.f / (1.f + expf(-rr.z)); rr.w = 1.f / (1.f + expf(-rr.w));
        }
        *(float4*)&out[(b * 96 + o) * 64000 + s0 + sg * 4] = rr;
    }
}

// ---------------- fused axial attention (qkv + scores + softmax + PV) ----------------
template <int AXIS, bool ACC>
__global__ __launch_bounds__(256) void k_attn(const float* __restrict__ xm,
                                              const float* __restrict__ qwt,  // [c][288]
                                              const float* __restrict__ qb,
                                              float* __restrict__ out) {
    __shared__ float xl[96 * 40];     // [c][l]
    __shared__ float qs[40][100];     // q: [l][m]
    __shared__ float kT[96][44];      // k: [m][l]
    __shared__ float vT[96][44];      // v: [m][l]
    int bid = blockIdx.x;
    int b = bid / 1600, r = bid % 1600;
    int offset, stride;
    if (AXIS == 0) { stride = 1600; offset = r; }
    else if (AXIS == 1) { stride = 40; offset = (r / 40) * 1600 + (r % 40); }
    else { stride = 1; offset = r * 40; }
    int t = threadIdx.x;
    const float* base = xm + b * 96 * 64000 + offset;
    for (int i = t; i < 96 * 40; i += 256) {
        int c = i / 40, l = i % 40;
        xl[c * 40 + l] = base[c * 64000 + l * stride];
    }
    __syncthreads();

    if (t < 240) {
        int lg = t / 24, mg = t % 24;
        int l0 = lg * 4, m0 = mg * 12;
        float acc[4][12];
#pragma unroll
        for (int l = 0; l < 4; l++)
#pragma unroll
            for (int j = 0; j < 12; j++) acc[l][j] = 0.f;
        for (int c = 0; c < 96; c++) {
            float4 xv = *(const float4*)&xl[c * 40 + l0];
            const float4* wp = (const float4*)&qwt[c * 288 + m0];
            float4 w0 = wp[0], w1 = wp[1], w2 = wp[2];
            float wv[12] = {w0.x, w0.y, w0.z, w0.w, w1.x, w1.y, w1.z, w1.w, w2.x, w2.y, w2.z, w2.w};
            float xf[4] = {xv.x, xv.y, xv.z, xv.w};
#pragma unroll
            for (int l = 0; l < 4; l++)
#pragma unroll
                for (int j = 0; j < 12; j++) acc[l][j] += xf[l] * wv[j];
        }
        float br[12];
#pragma unroll
        for (int j = 0; j < 12; j++) br[j] = qb[m0 + j];
#pragma unroll
        for (int l = 0; l < 4; l++) {
            int ll = l0 + l;
#pragma unroll
            for (int j = 0; j < 12; j++) {
                int m = m0 + j;
                float v = acc[l][j] + br[j];
                if (m < 96) qs[ll][m] = v;
                else if (m < 192) kT[m - 96][ll] = v;
                else vT[m - 192][ll] = v;
            }
        }
    }
    __syncthreads();

    if (t < 80) {
        int h = t / 20, qlp = t % 20;
        int ql0 = qlp * 2, ql1 = ql0 + 1;
        float s0r[40], s1r[40];
#pragma unroll
        for (int i = 0; i < 40; i++) { s0r[i] = 0.f; s1r[i] = 0.f; }
        for (int hd = 0; hd < 24; hd++) {
            float q0 = qs[ql0][h * 24 + hd];
            float q1 = qs[ql1][h * 24 + hd];
            const float4* kp = (const float4*)&kT[h * 24 + hd][0];
#pragma unroll
            for (int q4 = 0; q4 < 10; q4++) {
                float4 kv = kp[q4];
                s0r[4 * q4 + 0] += q0 * kv.x; s0r[4 * q4 + 1] += q0 * kv.y;
                s0r[4 * q4 + 2] += q0 * kv.z; s0r[4 * q4 + 3] += q0 * kv.w;
                s1r[4 * q4 + 0] += q1 * kv.x; s1r[4 * q4 + 1] += q1 * kv.y;
                s1r[4 * q4 + 2] += q1 * kv.z; s1r[4 * q4 + 3] += q1 * kv.w;
            }
        }
        const float scale = 0.20412414523193154f;
        float m0 = -1e30f, m1 = -1e30f;
#pragma unroll
        for (int i = 0; i < 40; i++) {
            s0r[i] *= scale; s1r[i] *= scale;
            m0 = fmaxf(m0, s0r[i]); m1 = fmaxf(m1, s1r[i]);
        }
        float sum0 = 0.f, sum1 = 0.f;
#pragma unroll
        for (int i = 0; i < 40; i++) {
            s0r[i] = expf(s0r[i] - m0); sum0 += s0r[i];
            s1r[i] = expf(s1r[i] - m1); sum1 += s1r[i];
        }
        float inv0 = 1.f / sum0, inv1 = 1.f / sum1;
        for (int hd = 0; hd < 24; hd++) {
            const float4* vp = (const float4*)&vT[h * 24 + hd][0];
            float o0 = 0.f, o1 = 0.f;
#pragma unroll
            for (int q4 = 0; q4 < 10; q4++) {
                float4 vv = vp[q4];
                o0 += s0r[4 * q4 + 0] * vv.x + s0r[4 * q4 + 1] * vv.y + s0r[4 * q4 + 2] * vv.z + s0r[4 * q4 + 3] * vv.w;
                o1 += s1r[4 * q4 + 0] * vv.x + s1r[4 * q4 + 1] * vv.y + s1r[4 * q4 + 2] * vv.z + s1r[4 * q4 + 3] * vv.w;
            }
            o0 *= inv0; o1 *= inv1;
            int cbase = (b * 96 + h * 24 + hd) * 64000 + offset;
            if (ACC) {
                out[cbase + ql0 * stride] += o0;
                out[cbase + ql1 * stride] += o1;
            } else {
                out[cbase + ql0 * stride] = o0;
                out[cbase + ql1 * stride] = o1;
            }
        }
    }
}

extern "C" void kernel_launch(void* const* d_in, const int* in_sizes, int n_in,
                              void* d_out, int out_size, void* d_ws, size_t ws_size,
                              hipStream_t stream) {
    const float* x      = (const float*)d_in[0];
    const float* pos    = (const float*)d_in[1];
    const float* qkv_w  = (const float*)d_in[2];
    const float* qkv_b  = (const float*)d_in[3];
    const float* lp1_w  = (const float*)d_in[4];
    const float* lp1_b  = (const float*)d_in[5];
    const float* lp2_w  = (const float*)d_in[6];
    const float* lp2_b  = (const float*)d_in[7];
    const float* mod1_w = (const float*)d_in[8];
    const float* mod1_b = (const float*)d_in[9];
    const float* mod2_w = (const float*)d_in[10];
    const float* mod2_b = (const float*)d_in[11];
    // d_in[12..16]: pa_w, pa_b, R6_d, R6_h, R6_w — provably no-ops (see header)
    const float* proj_w = (const float*)d_in[17];
    const float* proj_b = (const float*)d_in[18];
    float* out = (float*)d_out;
    float* ws = (float*)d_ws;

    float* buf0 = ws;                          // 12,288,000 floats
    float* buf1 = ws + 12288000;               // 12,288,000 floats
    float2* stats = (float2*)(ws + 24576000);  // 192 float2
    float* qwt = ws + 24576384;                // 27,648 floats [c][288]
    unsigned short* wb2 = (unsigned short*)(ws + 24604032);  // 248,832 bf16
    unsigned short* in_t = (unsigned short*)buf1;            // aliases buf1 (dead after conv3)

    k_cvt_in<<<2000, 256, 0, stream>>>(pos, in_t);
    k_cvt_w<<<972, 256, 0, stream>>>(lp1_w, wb2);
    k_transpose_qkvw<<<108, 256, 0, stream>>>(qkv_w, qwt);

    // local = conv1x1(gelu(IN(conv3(pos))))
    k_conv3_mfma<<<500, 256, 0, stream>>>(in_t, wb2, lp1_b, buf0);
    k_stats<<<192, 256, 0, stream>>>(buf0, stats);
    k_norm_gelu<<<12000, 256, 0, stream>>>(buf0, stats);
    k_conv1x1<0><<<2000, 256, 0, stream>>>(buf0, lp2_w, lp2_b, buf1);  // overwrites in_t (dead)

    // mod = sigmoid(conv1x1(gelu(IN(conv1x1(local)))))
    k_conv1x1<0><<<2000, 256, 0, stream>>>(buf1, mod1_w, mod1_b, buf0);
    k_stats<<<192, 256, 0, stream>>>(buf0, stats);
    k_norm_gelu<<<12000, 256, 0, stream>>>(buf0, stats);
    k_conv1x1<1><<<2000, 256, 0, stream>>>(buf0, mod2_w, mod2_b, buf1);

    // x_mod = x * mod
    k_xmod<<<12000, 256, 0, stream>>>((const float4*)x, (const float4*)buf1, (float4*)buf0);

    // axial attention: axis d writes, axes h/w accumulate
    k_attn<0, false><<<3200, 256, 0, stream>>>(buf0, qwt, qkv_b, buf1);
    k_attn<1, true ><<<3200, 256, 0, stream>>>(buf0, qwt, qkv_b, buf1);
    k_attn<2, true ><<<3200, 256, 0, stream>>>(buf0, qwt, qkv_b, buf1);

    // out = conv1x1(out_sum, proj)
    k_conv1x1<0><<<2000, 256, 0, stream>>>(buf1, proj_w, proj_b, out);
}

// Round 3
// 936.121 us; speedup vs baseline: 3.0570x; 1.6759x over previous
//
#include <hip/hip_runtime.h>

// Problem constants: B=2, C=96, D=H=W=40, S=64000, NH=4, HD=24, L=40
// Exact simplifications vs reference:
//  - pos_attn branch dropped (softmax row-shift invariance)
//  - R6 rotations dropped (R orthogonal; (Rq).(Rk) = q.k; v unrotated)
// Round 3: attention restructured. qkv projection hoisted into a per-axis MFMA
// GEMM writing axis-ordered f16 qA[b][r][l][288] (qkv bias + q-scale folded in);
// attention kernel is softmax+PV only using v_dot2_f32_f16; out_sum in
// [b][s][96] f32 (contiguous 384B/position); proj = MFMA GEMM.

typedef __attribute__((ext_vector_type(8))) short short8;
typedef __attribute__((ext_vector_type(8))) _Float16 half8;
typedef __attribute__((ext_vector_type(2))) _Float16 half2;
typedef __attribute__((ext_vector_type(16))) float floatx16;

static __device__ __forceinline__ unsigned short f2bf(float f) {
    unsigned int u = __builtin_bit_cast(unsigned int, f);
    u = u + 0x7FFFu + ((u >> 16) & 1u);   // RNE
    return (unsigned short)(u >> 16);
}
static __device__ __forceinline__ half2 h2(unsigned int u) {
    return __builtin_bit_cast(half2, u);
}
static __device__ __forceinline__ float fdot2(unsigned int a, unsigned int b, float c) {
    return __builtin_amdgcn_fdot2(h2(a), h2(b), c, false);
}

// ---------------- prep: pos fp32 [b][c][s] -> bf16 [b][s][c] (conv3 input) ----------------
__global__ __launch_bounds__(256) void k_cvt_in(const float* __restrict__ pos,
                                                unsigned short* __restrict__ in_t) {
    __shared__ unsigned short lds[64][97];
    int bid = blockIdx.x;
    int b = bid / 1000, s0 = (bid % 1000) * 64;
    int t = threadIdx.x;
    for (int i = t; i < 6144; i += 256) {
        int c = i / 64, sl = i % 64;
        lds[sl][c] = f2bf(pos[(b * 96 + c) * 64000 + s0 + sl]);
    }
    __syncthreads();
    unsigned short* outp = in_t + ((size_t)b * 64000 + s0) * 96;
    for (int i = t; i < 6144; i += 256) {
        int sl = i / 96, c = i % 96;
        outp[i] = lds[sl][c];
    }
}

// ---------------- prep: lp1_w [o][c][tap] -> bf16 wb2 [tap][o][c] ----------------
__global__ void k_cvt_w(const float* __restrict__ w, unsigned short* __restrict__ wb2) {
    int i = blockIdx.x * 256 + threadIdx.x;
    if (i < 248832) {
        int c = i % 96, m = (i / 96) % 96, tap = i / 9216;
        wb2[i] = f2bf(w[(m * 96 + c) * 27 + tap]);
    }
}

// ---------------- prep: f32 -> f16 straight copy (qkv_w 288x96, proj_w 96x96) ----------------
__global__ void k_cvt_f16(const float* __restrict__ w, _Float16* __restrict__ o, int n) {
    int i = blockIdx.x * 256 + threadIdx.x;
    if (i < n) o[i] = (_Float16)w[i];
}

// ---------------- conv 3x3x3 circular as bf16 MFMA implicit GEMM (unchanged) ----------------
__global__ __launch_bounds__(256) void k_conv3_mfma(const unsigned short* __restrict__ in_t,
                                                    const unsigned short* __restrict__ wb2,
                                                    const float* __restrict__ bias,
                                                    float* __restrict__ out) {
    __shared__ unsigned short A_lds[96 * 104];
    __shared__ int tbl[27 * 256];
    __shared__ float bsh[96];
    int t = threadIdx.x;
    int bid = blockIdx.x;
    int b = bid / 250;
    int s0 = (bid % 250) * 256;

    for (int u = t; u < 27 * 256; u += 256) {
        int tap = u >> 8, nl = u & 255;
        int kd = tap / 9, kh = (tap / 3) % 3, kw = tap % 3;
        int s = s0 + nl;
        int d = s / 1600, r = s - d * 1600;
        int h = r / 40, w = r - h * 40;
        int ds = d + kd - 1; if (ds < 0) ds += 40; else if (ds >= 40) ds -= 40;
        int hs = h + kh - 1; if (hs < 0) hs += 40; else if (hs >= 40) hs -= 40;
        int wv2 = w + kw - 1; if (wv2 < 0) wv2 += 40; else if (wv2 >= 40) wv2 -= 40;
        tbl[u] = ((ds * 1600 + hs * 40 + wv2) * 96) * 2;
    }
    if (t < 96) bsh[t] = bias[t];

    int wv = t >> 6;
    int lane = t & 63;
    int n31 = lane & 31;
    int kg = lane >> 5;

    const char* inb = (const char*)(in_t + (size_t)b * 64000 * 96) + kg * 16;

    floatx16 acc[3][2];
#pragma unroll
    for (int mt = 0; mt < 3; mt++)
#pragma unroll
        for (int nt = 0; nt < 2; nt++)
#pragma unroll
            for (int r = 0; r < 16; r++) acc[mt][nt][r] = 0.f;

    for (int tap = 0; tap < 27; tap++) {
        __syncthreads();
        const uint4* wsrc = (const uint4*)(wb2 + tap * 9216);
        for (int u = t; u < 1152; u += 256) {
            int m = u / 12, seg = u % 12;
            uint4 v = wsrc[u];
            *(uint4*)((char*)A_lds + m * 208 + seg * 16) = v;
        }
        __syncthreads();
        int ta0 = tbl[tap * 256 + wv * 64 + n31];
        int ta1 = tbl[tap * 256 + wv * 64 + 32 + n31];
        const char* pb0 = inb + ta0;
        const char* pb1 = inb + ta1;
#pragma unroll
        for (int j = 0; j < 6; j++) {
            short8 a0 = *(short8*)((char*)A_lds + (n31) * 208 + j * 32 + kg * 16);
            short8 a1 = *(short8*)((char*)A_lds + (32 + n31) * 208 + j * 32 + kg * 16);
            short8 a2 = *(short8*)((char*)A_lds + (64 + n31) * 208 + j * 32 + kg * 16);
            short8 b0 = *(const short8*)(pb0 + j * 32);
            short8 b1 = *(const short8*)(pb1 + j * 32);
            acc[0][0] = __builtin_amdgcn_mfma_f32_32x32x16_bf16(a0, b0, acc[0][0], 0, 0, 0);
            acc[0][1] = __builtin_amdgcn_mfma_f32_32x32x16_bf16(a0, b1, acc[0][1], 0, 0, 0);
            acc[1][0] = __builtin_amdgcn_mfma_f32_32x32x16_bf16(a1, b0, acc[1][0], 0, 0, 0);
            acc[1][1] = __builtin_amdgcn_mfma_f32_32x32x16_bf16(a1, b1, acc[1][1], 0, 0, 0);
            acc[2][0] = __builtin_amdgcn_mfma_f32_32x32x16_bf16(a2, b0, acc[2][0], 0, 0, 0);
            acc[2][1] = __builtin_amdgcn_mfma_f32_32x32x16_bf16(a2, b1, acc[2][1], 0, 0, 0);
        }
    }

    int sbase = s0 + wv * 64;
#pragma unroll
    for (int mt = 0; mt < 3; mt++)
#pragma unroll
        for (int nt = 0; nt < 2; nt++)
#pragma unroll
            for (int r = 0; r < 16; r++) {
                int o = mt * 32 + (r & 3) + 8 * (r >> 2) + 4 * kg;
                int s = sbase + nt * 32 + n31;
                out[(b * 96 + o) * 64000 + s] = acc[mt][nt][r] + bsh[o];
            }
}

// ---------------- instance-norm stats ----------------
__global__ __launch_bounds__(256) void k_stats(const float* __restrict__ in, float2* __restrict__ stats) {
    int bc = blockIdx.x;
    const float4* p = (const float4*)(in + (size_t)bc * 64000);
    int t = threadIdx.x;
    float s = 0.f, sq = 0.f;
    for (int i = t; i < 16000; i += 256) {
        float4 v = p[i];
        s += v.x + v.y + v.z + v.w;
        sq += v.x * v.x + v.y * v.y + v.z * v.z + v.w * v.w;
    }
    __shared__ float rs[256], rq[256];
    rs[t] = s; rq[t] = sq;
    __syncthreads();
    for (int off = 128; off > 0; off >>= 1) {
        if (t < off) { rs[t] += rs[t + off]; rq[t] += rq[t + off]; }
        __syncthreads();
    }
    if (t == 0) {
        float mu = rs[0] * (1.f / 64000.f);
        float var = rq[0] * (1.f / 64000.f) - mu * mu;
        stats[bc] = make_float2(mu, rsqrtf(var + 1e-5f));
    }
}

// ---------------- norm + gelu, in-place ----------------
__global__ __launch_bounds__(256) void k_norm_gelu(float* __restrict__ x, const float2* __restrict__ stats) {
    int i = blockIdx.x * 256 + threadIdx.x;
    int bc = i / 16000;
    float2 st = stats[bc];
    float4 v = ((const float4*)x)[i];
    float* f = &v.x;
#pragma unroll
    for (int q = 0; q < 4; q++) {
        float u = (f[q] - st.x) * st.y;
        f[q] = 0.5f * u * (1.f + erff(u * 0.70710678118654752f));
    }
    ((float4*)x)[i] = v;
}

// ---------------- x * mod, transposed to f16 [b][s][96] ----------------
__global__ __launch_bounds__(256) void k_xmod_t(const float* __restrict__ x, const float* __restrict__ m,
                                                _Float16* __restrict__ xt) {
    __shared__ _Float16 lds[64][104];
    int bid = blockIdx.x;
    int b = bid / 1000, s0 = (bid % 1000) * 64;
    int t = threadIdx.x;
    for (int i = t; i < 6144; i += 256) {
        int c = i / 64, sl = i % 64;
        int gi = (b * 96 + c) * 64000 + s0 + sl;
        lds[sl][c] = (_Float16)(x[gi] * m[gi]);
    }
    __syncthreads();
    for (int i = t; i < 768; i += 256) {
        int sl = i / 12, seg = i % 12;
        _Float16 tmp[8];
#pragma unroll
        for (int e = 0; e < 8; e++) tmp[e] = lds[sl][seg * 8 + e];
        *(uint4*)&xt[((size_t)(b * 64000 + s0 + sl)) * 96 + seg * 8] = *(uint4*)tmp;
    }
}

// ---------------- 1x1 conv (96x96), MODE 0=bias, 1=bias+sigmoid ----------------
template <int MODE>
__global__ __launch_bounds__(256) void k_conv1x1(const float* __restrict__ in,
                                                 const float* __restrict__ w,
                                                 const float* __restrict__ bias,
                                                 float* __restrict__ out) {
    __shared__ float wl[96][98];
    __shared__ float it[96][64];
    int bid = blockIdx.x;
    int b = bid / 1000;
    int s0 = (bid % 1000) * 64;
    int t = threadIdx.x;
    for (int i = t; i < 96 * 96; i += 256) wl[i % 96][i / 96] = w[i];
    for (int i = t; i < 96 * 64; i += 256) {
        int c = i / 64, sl = i % 64;
        it[c][sl] = in[(b * 96 + c) * 64000 + s0 + sl];
    }
    __syncthreads();
    int og = t / 16, sg = t % 16;
    float acc[6][4];
#pragma unroll
    for (int j = 0; j < 6; j++)
#pragma unroll
        for (int q = 0; q < 4; q++) acc[j][q] = 0.f;
    for (int c = 0; c < 96; c++) {
        float4 v = *(const float4*)&it[c][sg * 4];
#pragma unroll
        for (int j = 0; j < 6; j++) {
            float wv = wl[c][og * 6 + j];
            acc[j][0] += wv * v.x; acc[j][1] += wv * v.y; acc[j][2] += wv * v.z; acc[j][3] += wv * v.w;
        }
    }
#pragma unroll
    for (int j = 0; j < 6; j++) {
        int o = og * 6 + j;
        float bb = bias[o];
        float4 rr;
        rr.x = acc[j][0] + bb; rr.y = acc[j][1] + bb; rr.z = acc[j][2] + bb; rr.w = acc[j][3] + bb;
        if (MODE == 1) {
            rr.x = 1.f / (1.f + expf(-rr.x)); rr.y = 1.f / (1.f + expf(-rr.y));
            rr.z = 1.f / (1.f + expf(-rr.z)); rr.w = 1.f / (1.f + expf(-rr.w));
        }
        *(float4*)&out[(b * 96 + o) * 64000 + s0 + sg * 4] = rr;
    }
}

// ---------------- qkv GEMM per axis: qA[b][row][l][288] f16 ----------------
// M=288, K=96, N=128/block. Wave ws handles N-sub 32, all 9 M-tiles.
// q rows (m<96) get bias+scale folded; k,v rows get bias.
template <int AXIS>
__global__ __launch_bounds__(256) void k_qkv(const _Float16* __restrict__ xt,
                                             const _Float16* __restrict__ wq,  // [288][96]
                                             const float* __restrict__ qb,
                                             _Float16* __restrict__ qA) {
    __shared__ _Float16 smem[27648];   // union: A (288x96) then epi (64 x 296)
    __shared__ float bias_s[288];
    int t = threadIdx.x;
    int bid = blockIdx.x;
    int b = bid / 500;
    int s0 = (bid % 500) * 128;

    for (int i = t; i < 3456; i += 256) ((uint4*)smem)[i] = ((const uint4*)wq)[i];
    for (int i = t; i < 288; i += 256) bias_s[i] = qb[i];
    __syncthreads();

    int ws = t >> 6, lane = t & 63;
    int n = lane & 31, kg = lane >> 5;
    int p = ws * 32 + n;

    // B-frags: 6 K-chunks from xt row (s0+p)
    const uint4* brow = (const uint4*)(xt + ((size_t)(b * 64000 + s0 + p)) * 96);
    uint4 bf[6];
#pragma unroll
    for (int kc = 0; kc < 6; kc++) bf[kc] = brow[kc * 2 + kg];

    floatx16 acc[9];
#pragma unroll
    for (int mt = 0; mt < 9; mt++)
#pragma unroll
        for (int r = 0; r < 16; r++) acc[mt][r] = 0.f;

#pragma unroll
    for (int kc = 0; kc < 6; kc++) {
        half8 bfh = __builtin_bit_cast(half8, bf[kc]);
#pragma unroll
        for (int mt = 0; mt < 9; mt++) {
            uint4 au = *(const uint4*)&smem[(mt * 32 + n) * 96 + kc * 16 + kg * 8];
            acc[mt] = __builtin_amdgcn_mfma_f32_32x32x16_f16(__builtin_bit_cast(half8, au), bfh, acc[mt], 0, 0, 0);
        }
    }

    const float scale = 0.20412414523193154f;
    for (int q = 0; q < 2; q++) {
        __syncthreads();
        if ((ws >> 1) == q) {
            int pl = (ws & 1) * 32 + n;
#pragma unroll
            for (int mt = 0; mt < 9; mt++)
#pragma unroll
                for (int g = 0; g < 4; g++) {
                    int m0 = mt * 32 + g * 8 + kg * 4;
                    _Float16 tm[4];
#pragma unroll
                    for (int j = 0; j < 4; j++) {
                        float v = acc[mt][g * 4 + j] + bias_s[m0 + j];
                        if (m0 + j < 96) v *= scale;
                        tm[j] = (_Float16)v;
                    }
                    *(uint2*)&smem[pl * 296 + m0] = *(uint2*)tm;
                }
        }
        __syncthreads();
        for (int idx = t; idx < 2304; idx += 256) {
            int pl = idx / 36, seg = idx % 36;
            int s = s0 + q * 64 + pl;
            int row;
            if (AXIS == 0) { int l = s / 1600; row = (s - l * 1600) * 40 + l; }
            else if (AXIS == 1) { int d = s / 1600; int rem = s - d * 1600; int l = rem / 40; row = (d * 40 + (rem - l * 40)) * 40 + l; }
            else { row = s; }
            uint4 v = *(const uint4*)&smem[pl * 296 + seg * 8];
            *(uint4*)&qA[((size_t)(b * 64000 + row)) * 288 + seg * 8] = v;
        }
    }
}

// ---------------- fused axial attention: softmax + PV only ----------------
// block=320: 4 lines x (4 heads x 20 query-pairs). k rows + transposed V in LDS (f16).
template <int AXIS, bool ACC>
__global__ __launch_bounds__(320) void k_attn(const _Float16* __restrict__ qA,
                                              float* __restrict__ osum) {
    __shared__ _Float16 kk[15360];    // [line][key][96]
    __shared__ _Float16 vT[15488];    // plane lh=line*4+head stride 968; [hd][40 keys]
    int t = threadIdx.x;
    int bid = blockIdx.x;
    int b = bid / 400;
    int r0 = (bid % 400) * 4;

    const uint4* src = (const uint4*)qA;
    // stage k: contiguous
    for (int i = t; i < 1920; i += 320) {
        int line = i / 480, key = (i % 480) / 12, seg = i % 12;
        int row = (b * 1600 + r0 + line) * 40 + key;
        ((uint4*)kk)[i] = src[row * 36 + 12 + seg];
    }
    // stage v transposed
    for (int i = t; i < 1920; i += 320) {
        int line = i / 480, key = (i % 480) / 12, seg = i % 12;
        int row = (b * 1600 + r0 + line) * 40 + key;
        uint4 v = src[row * 36 + 24 + seg];
        _Float16 tmp[8];
        *(uint4*)tmp = v;
#pragma unroll
        for (int e = 0; e < 8; e++) {
            int hdg = seg * 8 + e;
            vT[(line * 4 + hdg / 24) * 968 + (hdg % 24) * 40 + key] = tmp[e];
        }
    }

    int line = t / 80, head = (t % 80) / 20, qp = t % 20;
    int rr = r0 + line;
    int ql0 = qp * 2, ql1 = ql0 + 1;
    // load q (scaled, biased) for both queries
    uint qu0[12], qu1[12];
    {
        const uint4* q0p = (const uint4*)(qA + ((size_t)((b * 1600 + rr) * 40 + ql0)) * 288 + head * 24);
        const uint4* q1p = (const uint4*)(qA + ((size_t)((b * 1600 + rr) * 40 + ql1)) * 288 + head * 24);
#pragma unroll
        for (int j = 0; j < 3; j++) { *(uint4*)&qu0[j * 4] = q0p[j]; *(uint4*)&qu1[j * 4] = q1p[j]; }
    }
    __syncthreads();

    float s0[40], s1[40];
    const uint4* kbase = (const uint4*)kk + line * 480 + head * 3;
#pragma unroll 4
    for (int key = 0; key < 40; key++) {
        uint kku[12];
#pragma unroll
        for (int j = 0; j < 3; j++) *(uint4*)&kku[j * 4] = kbase[key * 12 + j];
        float a0 = 0.f, a1 = 0.f;
#pragma unroll
        for (int i = 0; i < 12; i++) {
            a0 = fdot2(kku[i], qu0[i], a0);
            a1 = fdot2(kku[i], qu1[i], a1);
        }
        s0[key] = a0; s1[key] = a1;
    }

    float m0 = -1e30f, m1 = -1e30f;
#pragma unroll
    for (int i = 0; i < 40; i++) { m0 = fmaxf(m0, s0[i]); m1 = fmaxf(m1, s1[i]); }
    float sum0 = 0.f, sum1 = 0.f;
#pragma unroll
    for (int i = 0; i < 40; i++) {
        s0[i] = __expf(s0[i] - m0); sum0 += s0[i];
        s1[i] = __expf(s1[i] - m1); sum1 += s1[i];
    }
    float inv0 = 1.f / sum0, inv1 = 1.f / sum1;

    uint pw0[20], pw1[20];
#pragma unroll
    for (int i = 0; i < 20; i++) {
        half2 a = { (_Float16)(s0[2 * i] * inv0), (_Float16)(s0[2 * i + 1] * inv0) };
        half2 c = { (_Float16)(s1[2 * i] * inv1), (_Float16)(s1[2 * i + 1] * inv1) };
        pw0[i] = __builtin_bit_cast(unsigned int, a);
        pw1[i] = __builtin_bit_cast(unsigned int, c);
    }

    float o0[24], o1[24];
    const uint4* vbase = (const uint4*)vT + (line * 4 + head) * 121;
#pragma unroll 2
    for (int hd = 0; hd < 24; hd++) {
        uint vv[20];
#pragma unroll
        for (int j = 0; j < 5; j++) *(uint4*)&vv[j * 4] = vbase[hd * 5 + j];
        float a0 = 0.f, a1 = 0.f;
#pragma unroll
        for (int i = 0; i < 20; i++) {
            a0 = fdot2(vv[i], pw0[i], a0);
            a1 = fdot2(vv[i], pw1[i], a1);
        }
        o0[hd] = a0; o1[hd] = a1;
    }

    // output positions
    int sA, sB;
    if (AXIS == 0) { sA = ql0 * 1600 + rr; sB = ql1 * 1600 + rr; }
    else if (AXIS == 1) { int d = rr / 40, w = rr % 40; sA = d * 1600 + ql0 * 40 + w; sB = sA + 40; }
    else { sA = rr * 40 + ql0; sB = sA + 1; }
    float* pA = osum + ((size_t)(b * 64000 + sA)) * 96 + head * 24;
    float* pB = osum + ((size_t)(b * 64000 + sB)) * 96 + head * 24;
#pragma unroll
    for (int j = 0; j < 6; j++) {
        float4 vA = *(float4*)&o0[j * 4];
        float4 vB = *(float4*)&o1[j * 4];
        if (ACC) {
            float4 eA = ((float4*)pA)[j], eB = ((float4*)pB)[j];
            vA.x += eA.x; vA.y += eA.y; vA.z += eA.z; vA.w += eA.w;
            vB.x += eB.x; vB.y += eB.y; vB.z += eB.z; vB.w += eB.w;
        }
        ((float4*)pA)[j] = vA;
        ((float4*)pB)[j] = vB;
    }
}

// ---------------- proj GEMM: out[b][c][s] = proj_w @ out_sum[b][s][96] + b ----------------
__global__ __launch_bounds__(256) void k_proj(const float* __restrict__ osum,
                                              const _Float16* __restrict__ wp,  // [96][96]
                                              const float* __restrict__ pb,
                                              float* __restrict__ out) {
    __shared__ _Float16 A[9216];
    __shared__ float bias_s[96];
    int t = threadIdx.x;
    int bid = blockIdx.x;
    int b = bid / 500;
    int s0 = (bid % 500) * 128;
    for (int i = t; i < 1152; i += 256) ((uint4*)A)[i] = ((const uint4*)wp)[i];
    if (t < 96) bias_s[t] = pb[t];
    __syncthreads();

    int ws = t >> 6, lane = t & 63;
    int n = lane & 31, kg = lane >> 5;
    int p = ws * 32 + n;

    const float4* brow = (const float4*)(osum + ((size_t)(b * 64000 + s0 + p)) * 96);
    uint4 bf[6];
#pragma unroll
    for (int kc = 0; kc < 6; kc++) {
        float4 x0 = brow[kc * 4 + kg * 2], x1 = brow[kc * 4 + kg * 2 + 1];
        _Float16 tm[8] = { (_Float16)x0.x, (_Float16)x0.y, (_Float16)x0.z, (_Float16)x0.w,
                           (_Float16)x1.x, (_Float16)x1.y, (_Float16)x1.z, (_Float16)x1.w };
        bf[kc] = *(uint4*)tm;
    }

    floatx16 acc[3];
#pragma unroll
    for (int mt = 0; mt < 3; mt++)
#pragma unroll
        for (int r = 0; r < 16; r++) acc[mt][r] = 0.f;

#pragma unroll
    for (int kc = 0; kc < 6; kc++) {
        half8 bfh = __builtin_bit_cast(half8, bf[kc]);
#pragma unroll
        for (int mt = 0; mt < 3; mt++) {
            uint4 au = *(const uint4*)&A[(mt * 32 + n) * 96 + kc * 16 + kg * 8];
            acc[mt] = __builtin_amdgcn_mfma_f32_32x32x16_f16(__builtin_bit_cast(half8, au), bfh, acc[mt], 0, 0, 0);
        }
    }

#pragma unroll
    for (int mt = 0; mt < 3; mt++)
#pragma unroll
        for (int r = 0; r < 16; r++) {
            int m = mt * 32 + (r & 3) + 8 * (r >> 2) + 4 * kg;
            out[((size_t)(b * 96 + m)) * 64000 + s0 + ws * 32 + n] = acc[mt][r] + bias_s[m];
        }
}

extern "C" void kernel_launch(void* const* d_in, const int* in_sizes, int n_in,
                              void* d_out, int out_size, void* d_ws, size_t ws_size,
                              hipStream_t stream) {
    const float* x      = (const float*)d_in[0];
    const float* pos    = (const float*)d_in[1];
    const float* qkv_w  = (const float*)d_in[2];
    const float* qkv_b  = (const float*)d_in[3];
    const float* lp1_w  = (const float*)d_in[4];
    const float* lp1_b  = (const float*)d_in[5];
    const float* lp2_w  = (const float*)d_in[6];
    const float* lp2_b  = (const float*)d_in[7];
    const float* mod1_w = (const float*)d_in[8];
    const float* mod1_b = (const float*)d_in[9];
    const float* mod2_w = (const float*)d_in[10];
    const float* mod2_b = (const float*)d_in[11];
    // d_in[12..16]: pa_w, pa_b, R6_d, R6_h, R6_w — provably no-ops (see header)
    const float* proj_w = (const float*)d_in[17];
    const float* proj_b = (const float*)d_in[18];
    float* out = (float*)d_out;
    float* ws = (float*)d_ws;

    float* buf0 = ws;                          // 12,288,000 f32
    float* buf1 = ws + 12288000;               // 12,288,000 f32
    float2* stats = (float2*)(ws + 24576000);  // 192 float2
    unsigned short* wb2 = (unsigned short*)(ws + 24576384);   // 248,832 bf16
    _Float16* wq  = (_Float16*)(ws + 24700800);               // 27,648 f16
    _Float16* wpj = (_Float16*)(ws + 24714624);               // 9,216 f16
    _Float16* qA  = (_Float16*)(ws + 24720000);               // 36,864,000 f16
    unsigned short* in_t = (unsigned short*)buf1;             // bf16, dead after conv3
    _Float16* x_t = (_Float16*)buf0;                          // alias (after mod done)
    float* out_sum = buf1;                                    // alias (after x_t built)

    k_cvt_in<<<2000, 256, 0, stream>>>(pos, in_t);
    k_cvt_w<<<972, 256, 0, stream>>>(lp1_w, wb2);
    k_cvt_f16<<<108, 256, 0, stream>>>(qkv_w, wq, 27648);
    k_cvt_f16<<<36, 256, 0, stream>>>(proj_w, wpj, 9216);

    // local = conv1x1(gelu(IN(conv3(pos))))
    k_conv3_mfma<<<500, 256, 0, stream>>>(in_t, wb2, lp1_b, buf0);
    k_stats<<<192, 256, 0, stream>>>(buf0, stats);
    k_norm_gelu<<<12000, 256, 0, stream>>>(buf0, stats);
    k_conv1x1<0><<<2000, 256, 0, stream>>>(buf0, lp2_w, lp2_b, buf1);

    // mod = sigmoid(conv1x1(gelu(IN(conv1x1(local)))))
    k_conv1x1<0><<<2000, 256, 0, stream>>>(buf1, mod1_w, mod1_b, buf0);
    k_stats<<<192, 256, 0, stream>>>(buf0, stats);
    k_norm_gelu<<<12000, 256, 0, stream>>>(buf0, stats);
    k_conv1x1<1><<<2000, 256, 0, stream>>>(buf0, mod2_w, mod2_b, buf1);

    // x_mod (f16, [b][s][96]) into buf0 region
    k_xmod_t<<<2000, 256, 0, stream>>>(x, buf1, x_t);

    // per-axis: qkv GEMM into axis-ordered qA, then attention into out_sum (buf1)
    k_qkv<0><<<1000, 256, 0, stream>>>(x_t, wq, qkv_b, qA);
    k_attn<0, false><<<800, 320, 0, stream>>>(qA, out_sum);
    k_qkv<1><<<1000, 256, 0, stream>>>(x_t, wq, qkv_b, qA);
    k_attn<1, true ><<<800, 320, 0, stream>>>(qA, out_sum);
    k_qkv<2><<<1000, 256, 0, stream>>>(x_t, wq, qkv_b, qA);
    k_attn<2, true ><<<800, 320, 0, stream>>>(qA, out_sum);

    // out = proj(out_sum)
    k_proj<<<1000, 256, 0, stream>>>(out_sum, wpj, proj_b, out);
}

// Round 4
// 860.538 us; speedup vs baseline: 3.3255x; 1.0878x over previous
//
#include <hip/hip_runtime.h>

// Problem constants: B=2, C=96, D=H=W=40, S=64000, NH=4, HD=24, L=40
// Exact simplifications vs reference:
//  - pos_attn branch dropped (softmax row-shift invariance)
//  - R6 rotations dropped (R orthogonal; (Rq).(Rk) = q.k; v unrotated)
// Round 4: write-contiguous/gather-on-read attention path.
//  - k_qkv runs ONCE, qA[b][s][288] f16 in natural s-order (contiguous writes)
//  - k_attn<axis> gathers k/v/q rows from qA, writes o_a[b][row][96] f16
//    contiguously in line order (LDS-staged burst; no RMW, no scatter)
//  - k_proj fuses the 3-axis sum: gathers permuted rows of o0/o1/o2
//    (axis2 = identity) and accumulates 3 GEMMs into one epilogue.

typedef __attribute__((ext_vector_type(8))) short short8;
typedef __attribute__((ext_vector_type(8))) _Float16 half8;
typedef __attribute__((ext_vector_type(2))) _Float16 half2;
typedef __attribute__((ext_vector_type(16))) float floatx16;

static __device__ __forceinline__ unsigned short f2bf(float f) {
    unsigned int u = __builtin_bit_cast(unsigned int, f);
    u = u + 0x7FFFu + ((u >> 16) & 1u);   // RNE
    return (unsigned short)(u >> 16);
}
static __device__ __forceinline__ half2 h2(unsigned int u) {
    return __builtin_bit_cast(half2, u);
}
static __device__ __forceinline__ float fdot2(unsigned int a, unsigned int b, float c) {
    return __builtin_amdgcn_fdot2(h2(a), h2(b), c, false);
}

// ---------------- prep: pos fp32 [b][c][s] -> bf16 [b][s][c] (conv3 input) ----------------
__global__ __launch_bounds__(256) void k_cvt_in(const float* __restrict__ pos,
                                                unsigned short* __restrict__ in_t) {
    __shared__ unsigned short lds[64][97];
    int bid = blockIdx.x;
    int b = bid / 1000, s0 = (bid % 1000) * 64;
    int t = threadIdx.x;
    for (int i = t; i < 6144; i += 256) {
        int c = i / 64, sl = i % 64;
        lds[sl][c] = f2bf(pos[(b * 96 + c) * 64000 + s0 + sl]);
    }
    __syncthreads();
    unsigned short* outp = in_t + ((size_t)b * 64000 + s0) * 96;
    for (int i = t; i < 6144; i += 256) {
        int sl = i / 96, c = i % 96;
        outp[i] = lds[sl][c];
    }
}

// ---------------- prep: lp1_w [o][c][tap] -> bf16 wb2 [tap][o][c] ----------------
__global__ void k_cvt_w(const float* __restrict__ w, unsigned short* __restrict__ wb2) {
    int i = blockIdx.x * 256 + threadIdx.x;
    if (i < 248832) {
        int c = i % 96, m = (i / 96) % 96, tap = i / 9216;
        wb2[i] = f2bf(w[(m * 96 + c) * 27 + tap]);
    }
}

// ---------------- prep: f32 -> f16 straight copy ----------------
__global__ void k_cvt_f16(const float* __restrict__ w, _Float16* __restrict__ o, int n) {
    int i = blockIdx.x * 256 + threadIdx.x;
    if (i < n) o[i] = (_Float16)w[i];
}

// ---------------- conv 3x3x3 circular as bf16 MFMA implicit GEMM ----------------
__global__ __launch_bounds__(256) void k_conv3_mfma(const unsigned short* __restrict__ in_t,
                                                    const unsigned short* __restrict__ wb2,
                                                    const float* __restrict__ bias,
                                                    float* __restrict__ out) {
    __shared__ unsigned short A_lds[96 * 104];
    __shared__ int tbl[27 * 256];
    __shared__ float bsh[96];
    int t = threadIdx.x;
    int bid = blockIdx.x;
    int b = bid / 250;
    int s0 = (bid % 250) * 256;

    for (int u = t; u < 27 * 256; u += 256) {
        int tap = u >> 8, nl = u & 255;
        int kd = tap / 9, kh = (tap / 3) % 3, kw = tap % 3;
        int s = s0 + nl;
        int d = s / 1600, r = s - d * 1600;
        int h = r / 40, w = r - h * 40;
        int ds = d + kd - 1; if (ds < 0) ds += 40; else if (ds >= 40) ds -= 40;
        int hs = h + kh - 1; if (hs < 0) hs += 40; else if (hs >= 40) hs -= 40;
        int wv2 = w + kw - 1; if (wv2 < 0) wv2 += 40; else if (wv2 >= 40) wv2 -= 40;
        tbl[u] = ((ds * 1600 + hs * 40 + wv2) * 96) * 2;
    }
    if (t < 96) bsh[t] = bias[t];

    int wv = t >> 6;
    int lane = t & 63;
    int n31 = lane & 31;
    int kg = lane >> 5;

    const char* inb = (const char*)(in_t + (size_t)b * 64000 * 96) + kg * 16;

    floatx16 acc[3][2];
#pragma unroll
    for (int mt = 0; mt < 3; mt++)
#pragma unroll
        for (int nt = 0; nt < 2; nt++)
#pragma unroll
            for (int r = 0; r < 16; r++) acc[mt][nt][r] = 0.f;

    for (int tap = 0; tap < 27; tap++) {
        __syncthreads();
        const uint4* wsrc = (const uint4*)(wb2 + tap * 9216);
        for (int u = t; u < 1152; u += 256) {
            int m = u / 12, seg = u % 12;
            uint4 v = wsrc[u];
            *(uint4*)((char*)A_lds + m * 208 + seg * 16) = v;
        }
        __syncthreads();
        int ta0 = tbl[tap * 256 + wv * 64 + n31];
        int ta1 = tbl[tap * 256 + wv * 64 + 32 + n31];
        const char* pb0 = inb + ta0;
        const char* pb1 = inb + ta1;
#pragma unroll
        for (int j = 0; j < 6; j++) {
            short8 a0 = *(short8*)((char*)A_lds + (n31) * 208 + j * 32 + kg * 16);
            short8 a1 = *(short8*)((char*)A_lds + (32 + n31) * 208 + j * 32 + kg * 16);
            short8 a2 = *(short8*)((char*)A_lds + (64 + n31) * 208 + j * 32 + kg * 16);
            short8 b0 = *(const short8*)(pb0 + j * 32);
            short8 b1 = *(const short8*)(pb1 + j * 32);
            acc[0][0] = __builtin_amdgcn_mfma_f32_32x32x16_bf16(a0, b0, acc[0][0], 0, 0, 0);
            acc[0][1] = __builtin_amdgcn_mfma_f32_32x32x16_bf16(a0, b1, acc[0][1], 0, 0, 0);
            acc[1][0] = __builtin_amdgcn_mfma_f32_32x32x16_bf16(a1, b0, acc[1][0], 0, 0, 0);
            acc[1][1] = __builtin_amdgcn_mfma_f32_32x32x16_bf16(a1, b1, acc[1][1], 0, 0, 0);
            acc[2][0] = __builtin_amdgcn_mfma_f32_32x32x16_bf16(a2, b0, acc[2][0], 0, 0, 0);
            acc[2][1] = __builtin_amdgcn_mfma_f32_32x32x16_bf16(a2, b1, acc[2][1], 0, 0, 0);
        }
    }

    int sbase = s0 + wv * 64;
#pragma unroll
    for (int mt = 0; mt < 3; mt++)
#pragma unroll
        for (int nt = 0; nt < 2; nt++)
#pragma unroll
            for (int r = 0; r < 16; r++) {
                int o = mt * 32 + (r & 3) + 8 * (r >> 2) + 4 * kg;
                int s = sbase + nt * 32 + n31;
                out[(b * 96 + o) * 64000 + s] = acc[mt][nt][r] + bsh[o];
            }
}

// ---------------- instance-norm stats ----------------
__global__ __launch_bounds__(256) void k_stats(const float* __restrict__ in, float2* __restrict__ stats) {
    int bc = blockIdx.x;
    const float4* p = (const float4*)(in + (size_t)bc * 64000);
    int t = threadIdx.x;
    float s = 0.f, sq = 0.f;
    for (int i = t; i < 16000; i += 256) {
        float4 v = p[i];
        s += v.x + v.y + v.z + v.w;
        sq += v.x * v.x + v.y * v.y + v.z * v.z + v.w * v.w;
    }
    __shared__ float rs[256], rq[256];
    rs[t] = s; rq[t] = sq;
    __syncthreads();
    for (int off = 128; off > 0; off >>= 1) {
        if (t < off) { rs[t] += rs[t + off]; rq[t] += rq[t + off]; }
        __syncthreads();
    }
    if (t == 0) {
        float mu = rs[0] * (1.f / 64000.f);
        float var = rq[0] * (1.f / 64000.f) - mu * mu;
        stats[bc] = make_float2(mu, rsqrtf(var + 1e-5f));
    }
}

// ---------------- norm + gelu, in-place ----------------
__global__ __launch_bounds__(256) void k_norm_gelu(float* __restrict__ x, const float2* __restrict__ stats) {
    int i = blockIdx.x * 256 + threadIdx.x;
    int bc = i / 16000;
    float2 st = stats[bc];
    float4 v = ((const float4*)x)[i];
    float* f = &v.x;
#pragma unroll
    for (int q = 0; q < 4; q++) {
        float u = (f[q] - st.x) * st.y;
        f[q] = 0.5f * u * (1.f + erff(u * 0.70710678118654752f));
    }
    ((float4*)x)[i] = v;
}

// ---------------- x * mod, transposed to f16 [b][s][96] ----------------
__global__ __launch_bounds__(256) void k_xmod_t(const float* __restrict__ x, const float* __restrict__ m,
                                                _Float16* __restrict__ xt) {
    __shared__ _Float16 lds[64][104];
    int bid = blockIdx.x;
    int b = bid / 1000, s0 = (bid % 1000) * 64;
    int t = threadIdx.x;
    for (int i = t; i < 6144; i += 256) {
        int c = i / 64, sl = i % 64;
        int gi = (b * 96 + c) * 64000 + s0 + sl;
        lds[sl][c] = (_Float16)(x[gi] * m[gi]);
    }
    __syncthreads();
    for (int i = t; i < 768; i += 256) {
        int sl = i / 12, seg = i % 12;
        _Float16 tmp[8];
#pragma unroll
        for (int e = 0; e < 8; e++) tmp[e] = lds[sl][seg * 8 + e];
        *(uint4*)&xt[((size_t)(b * 64000 + s0 + sl)) * 96 + seg * 8] = *(uint4*)tmp;
    }
}

// ---------------- 1x1 conv (96x96), MODE 0=bias, 1=bias+sigmoid ----------------
template <int MODE>
__global__ __launch_bounds__(256) void k_conv1x1(const float* __restrict__ in,
                                                 const float* __restrict__ w,
                                                 const float* __restrict__ bias,
                                                 float* __restrict__ out) {
    __shared__ float wl[96][98];
    __shared__ float it[96][64];
    int bid = blockIdx.x;
    int b = bid / 1000;
    int s0 = (bid % 1000) * 64;
    int t = threadIdx.x;
    for (int i = t; i < 96 * 96; i += 256) wl[i % 96][i / 96] = w[i];
    for (int i = t; i < 96 * 64; i += 256) {
        int c = i / 64, sl = i % 64;
        it[c][sl] = in[(b * 96 + c) * 64000 + s0 + sl];
    }
    __syncthreads();
    int og = t / 16, sg = t % 16;
    float acc[6][4];
#pragma unroll
    for (int j = 0; j < 6; j++)
#pragma unroll
        for (int q = 0; q < 4; q++) acc[j][q] = 0.f;
    for (int c = 0; c < 96; c++) {
        float4 v = *(const float4*)&it[c][sg * 4];
#pragma unroll
        for (int j = 0; j < 6; j++) {
            float wv = wl[c][og * 6 + j];
            acc[j][0] += wv * v.x; acc[j][1] += wv * v.y; acc[j][2] += wv * v.z; acc[j][3] += wv * v.w;
        }
    }
#pragma unroll
    for (int j = 0; j < 6; j++) {
        int o = og * 6 + j;
        float bb = bias[o];
        float4 rr;
        rr.x = acc[j][0] + bb; rr.y = acc[j][1] + bb; rr.z = acc[j][2] + bb; rr.w = acc[j][3] + bb;
        if (MODE == 1) {
            rr.x = 1.f / (1.f + expf(-rr.x)); rr.y = 1.f / (1.f + expf(-rr.y));
            rr.z = 1.f / (1.f + expf(-rr.z)); rr.w = 1.f / (1.f + expf(-rr.w));
        }
        *(float4*)&out[(b * 96 + o) * 64000 + s0 + sg * 4] = rr;
    }
}

// ---------------- qkv GEMM (ONCE): qA[b][s][288] f16, natural s-order ----------------
__global__ __launch_bounds__(256) void k_qkv(const _Float16* __restrict__ xt,
                                             const _Float16* __restrict__ wq,  // [288][96]
                                             const float* __restrict__ qb,
                                             _Float16* __restrict__ qA) {
    __shared__ _Float16 smem[27648];   // union: A (288x96) then epi (64 x 296)
    __shared__ float bias_s[288];
    int t = threadIdx.x;
    int bid = blockIdx.x;
    int b = bid / 500;
    int s0 = (bid % 500) * 128;

    for (int i = t; i < 3456; i += 256) ((uint4*)smem)[i] = ((const uint4*)wq)[i];
    for (int i = t; i < 288; i += 256) bias_s[i] = qb[i];
    __syncthreads();

    int ws = t >> 6, lane = t & 63;
    int n = lane & 31, kg = lane >> 5;
    int p = ws * 32 + n;

    const uint4* brow = (const uint4*)(xt + ((size_t)(b * 64000 + s0 + p)) * 96);
    uint4 bf[6];
#pragma unroll
    for (int kc = 0; kc < 6; kc++) bf[kc] = brow[kc * 2 + kg];

    floatx16 acc[9];
#pragma unroll
    for (int mt = 0; mt < 9; mt++)
#pragma unroll
        for (int r = 0; r < 16; r++) acc[mt][r] = 0.f;

#pragma unroll
    for (int kc = 0; kc < 6; kc++) {
        half8 bfh = __builtin_bit_cast(half8, bf[kc]);
#pragma unroll
        for (int mt = 0; mt < 9; mt++) {
            uint4 au = *(const uint4*)&smem[(mt * 32 + n) * 96 + kc * 16 + kg * 8];
            acc[mt] = __builtin_amdgcn_mfma_f32_32x32x16_f16(__builtin_bit_cast(half8, au), bfh, acc[mt], 0, 0, 0);
        }
    }

    const float scale = 0.20412414523193154f;
    for (int q = 0; q < 2; q++) {
        __syncthreads();
        if ((ws >> 1) == q) {
            int pl = (ws & 1) * 32 + n;
#pragma unroll
            for (int mt = 0; mt < 9; mt++)
#pragma unroll
                for (int g = 0; g < 4; g++) {
                    int m0 = mt * 32 + g * 8 + kg * 4;
                    _Float16 tm[4];
#pragma unroll
                    for (int j = 0; j < 4; j++) {
                        float v = acc[mt][g * 4 + j] + bias_s[m0 + j];
                        if (m0 + j < 96) v *= scale;
                        tm[j] = (_Float16)v;
                    }
                    *(uint2*)&smem[pl * 296 + m0] = *(uint2*)tm;
                }
        }
        __syncthreads();
        for (int idx = t; idx < 2304; idx += 256) {
            int pl = idx / 36, seg = idx % 36;
            int s = s0 + q * 64 + pl;
            uint4 v = *(const uint4*)&smem[pl * 296 + seg * 8];
            *(uint4*)&qA[((size_t)(b * 64000 + s)) * 288 + seg * 8] = v;
        }
    }
}

// ---------------- fused axial attention: gather qkv rows, softmax + PV ----------------
// block=320: 4 lines x (4 heads x 20 query-pairs). Output o_a[b][row][96] f16,
// row = line*40 + l (contiguous per block).
template <int AXIS>
__global__ __launch_bounds__(320) void k_attn(const _Float16* __restrict__ qA,
                                              _Float16* __restrict__ oA) {
    __shared__ _Float16 kk[15360];    // [line][key][96] (reused for output staging)
    __shared__ _Float16 vT[15488];    // plane lh=line*4+head stride 968; [hd][40 keys]
    int t = threadIdx.x;
    int bid = blockIdx.x;
    int b = bid / 400;
    int r0 = (bid % 400) * 4;

    const uint4* src = (const uint4*)qA;
    // row index (within batch) of (line r, key l) in natural s-order
    auto smap = [&](int r, int l) -> int {
        if (AXIS == 0) return l * 1600 + r;
        else if (AXIS == 1) { int d = r / 40, w = r % 40; return d * 1600 + l * 40 + w; }
        else return r * 40 + l;
    };
    // stage k (ch 96..192)
    for (int i = t; i < 1920; i += 320) {
        int line = i / 480, key = (i % 480) / 12, seg = i % 12;
        int row = b * 64000 + smap(r0 + line, key);
        ((uint4*)kk)[i] = src[(size_t)row * 36 + 12 + seg];
    }
    // stage v transposed (ch 192..288)
    for (int i = t; i < 1920; i += 320) {
        int line = i / 480, key = (i % 480) / 12, seg = i % 12;
        int row = b * 64000 + smap(r0 + line, key);
        uint4 v = src[(size_t)row * 36 + 24 + seg];
        _Float16 tmp[8];
        *(uint4*)tmp = v;
#pragma unroll
        for (int e = 0; e < 8; e++) {
            int hdg = seg * 8 + e;
            vT[(line * 4 + hdg / 24) * 968 + (hdg % 24) * 40 + key] = tmp[e];
        }
    }

    int line = t / 80, head = (t % 80) / 20, qp = t % 20;
    int rr = r0 + line;
    int ql0 = qp * 2, ql1 = ql0 + 1;
    // q (scaled+biased) for both queries, gathered from global
    uint qu0[12], qu1[12];
    {
        const uint4* q0p = (const uint4*)(qA + ((size_t)(b * 64000 + smap(rr, ql0))) * 288 + head * 24);
        const uint4* q1p = (const uint4*)(qA + ((size_t)(b * 64000 + smap(rr, ql1))) * 288 + head * 24);
#pragma unroll
        for (int j = 0; j < 3; j++) { *(uint4*)&qu0[j * 4] = q0p[j]; *(uint4*)&qu1[j * 4] = q1p[j]; }
    }
    __syncthreads();

    float s0[40], s1[40];
    const uint4* kbase = (const uint4*)kk + line * 480 + head * 3;
#pragma unroll 4
    for (int key = 0; key < 40; key++) {
        uint kku[12];
#pragma unroll
        for (int j = 0; j < 3; j++) *(uint4*)&kku[j * 4] = kbase[key * 12 + j];
        float a0 = 0.f, a1 = 0.f;
#pragma unroll
        for (int i = 0; i < 12; i++) {
            a0 = fdot2(kku[i], qu0[i], a0);
            a1 = fdot2(kku[i], qu1[i], a1);
        }
        s0[key] = a0; s1[key] = a1;
    }

    float m0 = -1e30f, m1 = -1e30f;
#pragma unroll
    for (int i = 0; i < 40; i++) { m0 = fmaxf(m0, s0[i]); m1 = fmaxf(m1, s1[i]); }
    float sum0 = 0.f, sum1 = 0.f;
#pragma unroll
    for (int i = 0; i < 40; i++) {
        s0[i] = __expf(s0[i] - m0); sum0 += s0[i];
        s1[i] = __expf(s1[i] - m1); sum1 += s1[i];
    }
    float inv0 = 1.f / sum0, inv1 = 1.f / sum1;

    uint pw0[20], pw1[20];
#pragma unroll
    for (int i = 0; i < 20; i++) {
        half2 a = { (_Float16)(s0[2 * i] * inv0), (_Float16)(s0[2 * i + 1] * inv0) };
        half2 c = { (_Float16)(s1[2 * i] * inv1), (_Float16)(s1[2 * i + 1] * inv1) };
        pw0[i] = __builtin_bit_cast(unsigned int, a);
        pw1[i] = __builtin_bit_cast(unsigned int, c);
    }

    __syncthreads();   // all score-reads of kk done; kk becomes output staging

    float o0[24], o1[24];
    const uint4* vbase = (const uint4*)vT + (line * 4 + head) * 121;
#pragma unroll 2
    for (int hd = 0; hd < 24; hd++) {
        uint vv[20];
#pragma unroll
        for (int j = 0; j < 5; j++) *(uint4*)&vv[j * 4] = vbase[hd * 5 + j];
        float a0 = 0.f, a1 = 0.f;
#pragma unroll
        for (int i = 0; i < 20; i++) {
            a0 = fdot2(vv[i], pw0[i], a0);
            a1 = fdot2(vv[i], pw1[i], a1);
        }
        o0[hd] = a0; o1[hd] = a1;
    }

    // stage outputs into kk region: [line][l][96] f16
    {
        _Float16 tmA[24], tmB[24];
#pragma unroll
        for (int j = 0; j < 24; j++) { tmA[j] = (_Float16)o0[j]; tmB[j] = (_Float16)o1[j]; }
        _Float16* dA = &kk[(line * 40 + ql0) * 96 + head * 24];
        _Float16* dB = &kk[(line * 40 + ql1) * 96 + head * 24];
#pragma unroll
        for (int j = 0; j < 3; j++) {
            ((uint4*)dA)[j] = ((uint4*)tmA)[j];
            ((uint4*)dB)[j] = ((uint4*)tmB)[j];
        }
    }
    __syncthreads();

    // contiguous flush: 160 rows x 96 f16 = 1920 uint4
    uint4* dst = (uint4*)oA + ((size_t)(b * 64000 + r0 * 40)) * 12;
    for (int i = t; i < 1920; i += 320) dst[i] = ((uint4*)kk)[i];
}

// ---------------- proj GEMM with fused 3-axis sum ----------------
// out[b][c][s] = proj_w @ (o0[perm0(s)] + o1[perm1(s)] + o2[s]) + pb
__global__ __launch_bounds__(256) void k_proj(const _Float16* __restrict__ o0,
                                              const _Float16* __restrict__ o1,
                                              const _Float16* __restrict__ o2,
                                              const _Float16* __restrict__ wp,  // [96][96]
                                              const float* __restrict__ pb,
                                              float* __restrict__ out) {
    __shared__ _Float16 A[9216];
    __shared__ float bias_s[96];
    int t = threadIdx.x;
    int bid = blockIdx.x;
    int b = bid / 500;
    int s0 = (bid % 500) * 128;
    for (int i = t; i < 1152; i += 256) ((uint4*)A)[i] = ((const uint4*)wp)[i];
    if (t < 96) bias_s[t] = pb[t];
    __syncthreads();

    int ws = t >> 6, lane = t & 63;
    int n = lane & 31, kg = lane >> 5;
    int s = s0 + ws * 32 + n;

    // inverse permutations: row in o_a (within batch) holding position s
    int l0 = s / 1600, r0v = s % 1600;
    int row0 = r0v * 40 + l0;
    int d = s / 1600, rem = s % 1600, lh = rem / 40, wq2 = rem % 40;
    int row1 = (d * 40 + wq2) * 40 + lh;
    int row2 = s;

    const uint4* p0 = (const uint4*)(o0 + ((size_t)(b * 64000 + row0)) * 96);
    const uint4* p1 = (const uint4*)(o1 + ((size_t)(b * 64000 + row1)) * 96);
    const uint4* p2 = (const uint4*)(o2 + ((size_t)(b * 64000 + row2)) * 96);

    uint4 bf[3][6];
#pragma unroll
    for (int kc = 0; kc < 6; kc++) {
        bf[0][kc] = p0[kc * 2 + kg];
        bf[1][kc] = p1[kc * 2 + kg];
        bf[2][kc] = p2[kc * 2 + kg];
    }

    floatx16 acc[3];
#pragma unroll
    for (int mt = 0; mt < 3; mt++)
#pragma unroll
        for (int r = 0; r < 16; r++) acc[mt][r] = 0.f;

#pragma unroll
    for (int kc = 0; kc < 6; kc++) {
#pragma unroll
        for (int mt = 0; mt < 3; mt++) {
            uint4 au = *(const uint4*)&A[(mt * 32 + n) * 96 + kc * 16 + kg * 8];
            half8 ah = __builtin_bit_cast(half8, au);
            acc[mt] = __builtin_amdgcn_mfma_f32_32x32x16_f16(ah, __builtin_bit_cast(half8, bf[0][kc]), acc[mt], 0, 0, 0);
            acc[mt] = __builtin_amdgcn_mfma_f32_32x32x16_f16(ah, __builtin_bit_cast(half8, bf[1][kc]), acc[mt], 0, 0, 0);
            acc[mt] = __builtin_amdgcn_mfma_f32_32x32x16_f16(ah, __builtin_bit_cast(half8, bf[2][kc]), acc[mt], 0, 0, 0);
        }
    }

#pragma unroll
    for (int mt = 0; mt < 3; mt++)
#pragma unroll
        for (int r = 0; r < 16; r++) {
            int m = mt * 32 + (r & 3) + 8 * (r >> 2) + 4 * kg;
            out[((size_t)(b * 96 + m)) * 64000 + s] = acc[mt][r] + bias_s[m];
        }
}

extern "C" void kernel_launch(void* const* d_in, const int* in_sizes, int n_in,
                              void* d_out, int out_size, void* d_ws, size_t ws_size,
                              hipStream_t stream) {
    const float* x      = (const float*)d_in[0];
    const float* pos    = (const float*)d_in[1];
    const float* qkv_w  = (const float*)d_in[2];
    const float* qkv_b  = (const float*)d_in[3];
    const float* lp1_w  = (const float*)d_in[4];
    const float* lp1_b  = (const float*)d_in[5];
    const float* lp2_w  = (const float*)d_in[6];
    const float* lp2_b  = (const float*)d_in[7];
    const float* mod1_w = (const float*)d_in[8];
    const float* mod1_b = (const float*)d_in[9];
    const float* mod2_w = (const float*)d_in[10];
    const float* mod2_b = (const float*)d_in[11];
    // d_in[12..16]: pa_w, pa_b, R6_d, R6_h, R6_w — provably no-ops (see header)
    const float* proj_w = (const float*)d_in[17];
    const float* proj_b = (const float*)d_in[18];
    float* out = (float*)d_out;
    float* ws = (float*)d_ws;

    float* buf0 = ws;                          // 12,288,000 f32
    float* buf1 = ws + 12288000;               // 12,288,000 f32
    float2* stats = (float2*)(ws + 24576000);  // 192 float2
    unsigned short* wb2 = (unsigned short*)(ws + 24576384);   // 248,832 bf16
    _Float16* wq  = (_Float16*)(ws + 24700800);               // 27,648 f16
    _Float16* wpj = (_Float16*)(ws + 24714624);               // 9,216 f16
    _Float16* qA  = (_Float16*)(ws + 24720000);               // 36,864,000 f16
    unsigned short* in_t = (unsigned short*)buf1;             // bf16, dead after conv3
    _Float16* x_t = (_Float16*)buf0;                          // buf0 lower half (12.288M f16)
    _Float16* o2  = (_Float16*)(buf0 + 6144000);              // buf0 upper half
    _Float16* o0  = (_Float16*)buf1;                          // buf1 lower half
    _Float16* o1  = (_Float16*)buf1 + 12288000;               // buf1 upper half

    k_cvt_in<<<2000, 256, 0, stream>>>(pos, in_t);
    k_cvt_w<<<972, 256, 0, stream>>>(lp1_w, wb2);
    k_cvt_f16<<<108, 256, 0, stream>>>(qkv_w, wq, 27648);
    k_cvt_f16<<<36, 256, 0, stream>>>(proj_w, wpj, 9216);

    // local = conv1x1(gelu(IN(conv3(pos))))
    k_conv3_mfma<<<500, 256, 0, stream>>>(in_t, wb2, lp1_b, buf0);
    k_stats<<<192, 256, 0, stream>>>(buf0, stats);
    k_norm_gelu<<<12000, 256, 0, stream>>>(buf0, stats);
    k_conv1x1<0><<<2000, 256, 0, stream>>>(buf0, lp2_w, lp2_b, buf1);

    // mod = sigmoid(conv1x1(gelu(IN(conv1x1(local)))))
    k_conv1x1<0><<<2000, 256, 0, stream>>>(buf1, mod1_w, mod1_b, buf0);
    k_stats<<<192, 256, 0, stream>>>(buf0, stats);
    k_norm_gelu<<<12000, 256, 0, stream>>>(buf0, stats);
    k_conv1x1<1><<<2000, 256, 0, stream>>>(buf0, mod2_w, mod2_b, buf1);

    // x_mod (f16, [b][s][96]) into buf0 lower half
    k_xmod_t<<<2000, 256, 0, stream>>>(x, buf1, x_t);

    // qkv ONCE (s-order), then per-axis attention into per-axis o buffers
    k_qkv<<<1000, 256, 0, stream>>>(x_t, wq, qkv_b, qA);
    k_attn<0><<<800, 320, 0, stream>>>(qA, o0);
    k_attn<1><<<800, 320, 0, stream>>>(qA, o1);
    k_attn<2><<<800, 320, 0, stream>>>(qA, o2);

    // out = proj(o0 + o1 + o2) with fused permuted gather
    k_proj<<<1000, 256, 0, stream>>>(o0, o1, o2, wpj, proj_b, out);
}

// Round 5
// 748.764 us; speedup vs baseline: 3.8219x; 1.1493x over previous
//
#include <hip/hip_runtime.h>

// Problem constants: B=2, C=96, D=H=W=40, S=64000, NH=4, HD=24, L=40
// Exact simplifications vs reference:
//  - pos_attn branch dropped (softmax row-shift invariance)
//  - R6 rotations dropped (R orthogonal; (Rq).(Rk) = q.k; v unrotated)
// Round 5: k_attn de-spilled. Evidence: VGPR_Count=84 with ~120-float live set
// -> compiler spilled score arrays to scratch = the "7x write amplification"
// (172 MB vs 24.6 MB ideal, exactly matching 256k threads x ~575 B spills).
// Fix: 1 query/thread (2 lines/block), __launch_bounds__(320,3) for ~170 VGPR
// cap, 32 KB LDS, padded output staging (104 f16/row) + contiguous flush.

typedef __attribute__((ext_vector_type(8))) short short8;
typedef __attribute__((ext_vector_type(8))) _Float16 half8;
typedef __attribute__((ext_vector_type(2))) _Float16 half2;
typedef __attribute__((ext_vector_type(16))) float floatx16;

static __device__ __forceinline__ unsigned short f2bf(float f) {
    unsigned int u = __builtin_bit_cast(unsigned int, f);
    u = u + 0x7FFFu + ((u >> 16) & 1u);   // RNE
    return (unsigned short)(u >> 16);
}
static __device__ __forceinline__ half2 h2(unsigned int u) {
    return __builtin_bit_cast(half2, u);
}
static __device__ __forceinline__ float fdot2(unsigned int a, unsigned int b, float c) {
    return __builtin_amdgcn_fdot2(h2(a), h2(b), c, false);
}

// ---------------- prep: pos fp32 [b][c][s] -> bf16 [b][s][c] (conv3 input) ----------------
__global__ __launch_bounds__(256) void k_cvt_in(const float* __restrict__ pos,
                                                unsigned short* __restrict__ in_t) {
    __shared__ unsigned short lds[64][97];
    int bid = blockIdx.x;
    int b = bid / 1000, s0 = (bid % 1000) * 64;
    int t = threadIdx.x;
    for (int i = t; i < 6144; i += 256) {
        int c = i / 64, sl = i % 64;
        lds[sl][c] = f2bf(pos[(b * 96 + c) * 64000 + s0 + sl]);
    }
    __syncthreads();
    unsigned short* outp = in_t + ((size_t)b * 64000 + s0) * 96;
    for (int i = t; i < 6144; i += 256) {
        int sl = i / 96, c = i % 96;
        outp[i] = lds[sl][c];
    }
}

// ---------------- prep: lp1_w [o][c][tap] -> bf16 wb2 [tap][o][c] ----------------
__global__ void k_cvt_w(const float* __restrict__ w, unsigned short* __restrict__ wb2) {
    int i = blockIdx.x * 256 + threadIdx.x;
    if (i < 248832) {
        int c = i % 96, m = (i / 96) % 96, tap = i / 9216;
        wb2[i] = f2bf(w[(m * 96 + c) * 27 + tap]);
    }
}

// ---------------- prep: f32 -> f16 straight copy ----------------
__global__ void k_cvt_f16(const float* __restrict__ w, _Float16* __restrict__ o, int n) {
    int i = blockIdx.x * 256 + threadIdx.x;
    if (i < n) o[i] = (_Float16)w[i];
}

// ---------------- conv 3x3x3 circular as bf16 MFMA implicit GEMM ----------------
__global__ __launch_bounds__(256) void k_conv3_mfma(const unsigned short* __restrict__ in_t,
                                                    const unsigned short* __restrict__ wb2,
                                                    const float* __restrict__ bias,
                                                    float* __restrict__ out) {
    __shared__ unsigned short A_lds[96 * 104];
    __shared__ int tbl[27 * 256];
    __shared__ float bsh[96];
    int t = threadIdx.x;
    int bid = blockIdx.x;
    int b = bid / 250;
    int s0 = (bid % 250) * 256;

    for (int u = t; u < 27 * 256; u += 256) {
        int tap = u >> 8, nl = u & 255;
        int kd = tap / 9, kh = (tap / 3) % 3, kw = tap % 3;
        int s = s0 + nl;
        int d = s / 1600, r = s - d * 1600;
        int h = r / 40, w = r - h * 40;
        int ds = d + kd - 1; if (ds < 0) ds += 40; else if (ds >= 40) ds -= 40;
        int hs = h + kh - 1; if (hs < 0) hs += 40; else if (hs >= 40) hs -= 40;
        int wv2 = w + kw - 1; if (wv2 < 0) wv2 += 40; else if (wv2 >= 40) wv2 -= 40;
        tbl[u] = ((ds * 1600 + hs * 40 + wv2) * 96) * 2;
    }
    if (t < 96) bsh[t] = bias[t];

    int wv = t >> 6;
    int lane = t & 63;
    int n31 = lane & 31;
    int kg = lane >> 5;

    const char* inb = (const char*)(in_t + (size_t)b * 64000 * 96) + kg * 16;

    floatx16 acc[3][2];
#pragma unroll
    for (int mt = 0; mt < 3; mt++)
#pragma unroll
        for (int nt = 0; nt < 2; nt++)
#pragma unroll
            for (int r = 0; r < 16; r++) acc[mt][nt][r] = 0.f;

    for (int tap = 0; tap < 27; tap++) {
        __syncthreads();
        const uint4* wsrc = (const uint4*)(wb2 + tap * 9216);
        for (int u = t; u < 1152; u += 256) {
            int m = u / 12, seg = u % 12;
            uint4 v = wsrc[u];
            *(uint4*)((char*)A_lds + m * 208 + seg * 16) = v;
        }
        __syncthreads();
        int ta0 = tbl[tap * 256 + wv * 64 + n31];
        int ta1 = tbl[tap * 256 + wv * 64 + 32 + n31];
        const char* pb0 = inb + ta0;
        const char* pb1 = inb + ta1;
#pragma unroll
        for (int j = 0; j < 6; j++) {
            short8 a0 = *(short8*)((char*)A_lds + (n31) * 208 + j * 32 + kg * 16);
            short8 a1 = *(short8*)((char*)A_lds + (32 + n31) * 208 + j * 32 + kg * 16);
            short8 a2 = *(short8*)((char*)A_lds + (64 + n31) * 208 + j * 32 + kg * 16);
            short8 b0 = *(const short8*)(pb0 + j * 32);
            short8 b1 = *(const short8*)(pb1 + j * 32);
            acc[0][0] = __builtin_amdgcn_mfma_f32_32x32x16_bf16(a0, b0, acc[0][0], 0, 0, 0);
            acc[0][1] = __builtin_amdgcn_mfma_f32_32x32x16_bf16(a0, b1, acc[0][1], 0, 0, 0);
            acc[1][0] = __builtin_amdgcn_mfma_f32_32x32x16_bf16(a1, b0, acc[1][0], 0, 0, 0);
            acc[1][1] = __builtin_amdgcn_mfma_f32_32x32x16_bf16(a1, b1, acc[1][1], 0, 0, 0);
            acc[2][0] = __builtin_amdgcn_mfma_f32_32x32x16_bf16(a2, b0, acc[2][0], 0, 0, 0);
            acc[2][1] = __builtin_amdgcn_mfma_f32_32x32x16_bf16(a2, b1, acc[2][1], 0, 0, 0);
        }
    }

    int sbase = s0 + wv * 64;
#pragma unroll
    for (int mt = 0; mt < 3; mt++)
#pragma unroll
        for (int nt = 0; nt < 2; nt++)
#pragma unroll
            for (int r = 0; r < 16; r++) {
                int o = mt * 32 + (r & 3) + 8 * (r >> 2) + 4 * kg;
                int s = sbase + nt * 32 + n31;
                out[(b * 96 + o) * 64000 + s] = acc[mt][nt][r] + bsh[o];
            }
}

// ---------------- instance-norm stats ----------------
__global__ __launch_bounds__(256) void k_stats(const float* __restrict__ in, float2* __restrict__ stats) {
    int bc = blockIdx.x;
    const float4* p = (const float4*)(in + (size_t)bc * 64000);
    int t = threadIdx.x;
    float s = 0.f, sq = 0.f;
    for (int i = t; i < 16000; i += 256) {
        float4 v = p[i];
        s += v.x + v.y + v.z + v.w;
        sq += v.x * v.x + v.y * v.y + v.z * v.z + v.w * v.w;
    }
    __shared__ float rs[256], rq[256];
    rs[t] = s; rq[t] = sq;
    __syncthreads();
    for (int off = 128; off > 0; off >>= 1) {
        if (t < off) { rs[t] += rs[t + off]; rq[t] += rq[t + off]; }
        __syncthreads();
    }
    if (t == 0) {
        float mu = rs[0] * (1.f / 64000.f);
        float var = rq[0] * (1.f / 64000.f) - mu * mu;
        stats[bc] = make_float2(mu, rsqrtf(var + 1e-5f));
    }
}

// ---------------- norm + gelu, in-place ----------------
__global__ __launch_bounds__(256) void k_norm_gelu(float* __restrict__ x, const float2* __restrict__ stats) {
    int i = blockIdx.x * 256 + threadIdx.x;
    int bc = i / 16000;
    float2 st = stats[bc];
    float4 v = ((const float4*)x)[i];
    float* f = &v.x;
#pragma unroll
    for (int q = 0; q < 4; q++) {
        float u = (f[q] - st.x) * st.y;
        f[q] = 0.5f * u * (1.f + erff(u * 0.70710678118654752f));
    }
    ((float4*)x)[i] = v;
}

// ---------------- x * mod, transposed to f16 [b][s][96] ----------------
__global__ __launch_bounds__(256) void k_xmod_t(const float* __restrict__ x, const float* __restrict__ m,
                                                _Float16* __restrict__ xt) {
    __shared__ _Float16 lds[64][104];
    int bid = blockIdx.x;
    int b = bid / 1000, s0 = (bid % 1000) * 64;
    int t = threadIdx.x;
    for (int i = t; i < 6144; i += 256) {
        int c = i / 64, sl = i % 64;
        int gi = (b * 96 + c) * 64000 + s0 + sl;
        lds[sl][c] = (_Float16)(x[gi] * m[gi]);
    }
    __syncthreads();
    for (int i = t; i < 768; i += 256) {
        int sl = i / 12, seg = i % 12;
        _Float16 tmp[8];
#pragma unroll
        for (int e = 0; e < 8; e++) tmp[e] = lds[sl][seg * 8 + e];
        *(uint4*)&xt[((size_t)(b * 64000 + s0 + sl)) * 96 + seg * 8] = *(uint4*)tmp;
    }
}

// ---------------- 1x1 conv (96x96), MODE 0=bias, 1=bias+sigmoid ----------------
template <int MODE>
__global__ __launch_bounds__(256) void k_conv1x1(const float* __restrict__ in,
                                                 const float* __restrict__ w,
                                                 const float* __restrict__ bias,
                                                 float* __restrict__ out) {
    __shared__ float wl[96][98];
    __shared__ float it[96][64];
    int bid = blockIdx.x;
    int b = bid / 1000;
    int s0 = (bid % 1000) * 64;
    int t = threadIdx.x;
    for (int i = t; i < 96 * 96; i += 256) wl[i % 96][i / 96] = w[i];
    for (int i = t; i < 96 * 64; i += 256) {
        int c = i / 64, sl = i % 64;
        it[c][sl] = in[(b * 96 + c) * 64000 + s0 + sl];
    }
    __syncthreads();
    int og = t / 16, sg = t % 16;
    float acc[6][4];
#pragma unroll
    for (int j = 0; j < 6; j++)
#pragma unroll
        for (int q = 0; q < 4; q++) acc[j][q] = 0.f;
    for (int c = 0; c < 96; c++) {
        float4 v = *(const float4*)&it[c][sg * 4];
#pragma unroll
        for (int j = 0; j < 6; j++) {
            float wv = wl[c][og * 6 + j];
            acc[j][0] += wv * v.x; acc[j][1] += wv * v.y; acc[j][2] += wv * v.z; acc[j][3] += wv * v.w;
        }
    }
#pragma unroll
    for (int j = 0; j < 6; j++) {
        int o = og * 6 + j;
        float bb = bias[o];
        float4 rr;
        rr.x = acc[j][0] + bb; rr.y = acc[j][1] + bb; rr.z = acc[j][2] + bb; rr.w = acc[j][3] + bb;
        if (MODE == 1) {
            rr.x = 1.f / (1.f + expf(-rr.x)); rr.y = 1.f / (1.f + expf(-rr.y));
            rr.z = 1.f / (1.f + expf(-rr.z)); rr.w = 1.f / (1.f + expf(-rr.w));
        }
        *(float4*)&out[(b * 96 + o) * 64000 + s0 + sg * 4] = rr;
    }
}

// ---------------- qkv GEMM (ONCE): qA[b][s][288] f16, natural s-order ----------------
__global__ __launch_bounds__(256) void k_qkv(const _Float16* __restrict__ xt,
                                             const _Float16* __restrict__ wq,  // [288][96]
                                             const float* __restrict__ qb,
                                             _Float16* __restrict__ qA) {
    __shared__ _Float16 smem[27648];   // union: A (288x96) then epi (64 x 296)
    __shared__ float bias_s[288];
    int t = threadIdx.x;
    int bid = blockIdx.x;
    int b = bid / 500;
    int s0 = (bid % 500) * 128;

    for (int i = t; i < 3456; i += 256) ((uint4*)smem)[i] = ((const uint4*)wq)[i];
    for (int i = t; i < 288; i += 256) bias_s[i] = qb[i];
    __syncthreads();

    int ws = t >> 6, lane = t & 63;
    int n = lane & 31, kg = lane >> 5;
    int p = ws * 32 + n;

    const uint4* brow = (const uint4*)(xt + ((size_t)(b * 64000 + s0 + p)) * 96);
    uint4 bf[6];
#pragma unroll
    for (int kc = 0; kc < 6; kc++) bf[kc] = brow[kc * 2 + kg];

    floatx16 acc[9];
#pragma unroll
    for (int mt = 0; mt < 9; mt++)
#pragma unroll
        for (int r = 0; r < 16; r++) acc[mt][r] = 0.f;

#pragma unroll
    for (int kc = 0; kc < 6; kc++) {
        half8 bfh = __builtin_bit_cast(half8, bf[kc]);
#pragma unroll
        for (int mt = 0; mt < 9; mt++) {
            uint4 au = *(const uint4*)&smem[(mt * 32 + n) * 96 + kc * 16 + kg * 8];
            acc[mt] = __builtin_amdgcn_mfma_f32_32x32x16_f16(__builtin_bit_cast(half8, au), bfh, acc[mt], 0, 0, 0);
        }
    }

    const float scale = 0.20412414523193154f;
    for (int q = 0; q < 2; q++) {
        __syncthreads();
        if ((ws >> 1) == q) {
            int pl = (ws & 1) * 32 + n;
#pragma unroll
            for (int mt = 0; mt < 9; mt++)
#pragma unroll
                for (int g = 0; g < 4; g++) {
                    int m0 = mt * 32 + g * 8 + kg * 4;
                    _Float16 tm[4];
#pragma unroll
                    for (int j = 0; j < 4; j++) {
                        float v = acc[mt][g * 4 + j] + bias_s[m0 + j];
                        if (m0 + j < 96) v *= scale;
                        tm[j] = (_Float16)v;
                    }
                    *(uint2*)&smem[pl * 296 + m0] = *(uint2*)tm;
                }
        }
        __syncthreads();
        for (int idx = t; idx < 2304; idx += 256) {
            int pl = idx / 36, seg = idx % 36;
            int s = s0 + q * 64 + pl;
            uint4 v = *(const uint4*)&smem[pl * 296 + seg * 8];
            *(uint4*)&qA[((size_t)(b * 64000 + s)) * 288 + seg * 8] = v;
        }
    }
}

// ---------------- fused axial attention: gather qkv rows, softmax + PV ----------------
// block=320: 2 lines x (4 heads x 40 queries), ONE query per thread.
// __launch_bounds__(320,3): ~170 VGPR cap -> no scratch spills (round-4 lesson).
template <int AXIS>
__global__ __launch_bounds__(320, 3) void k_attn(const _Float16* __restrict__ qA,
                                                 _Float16* __restrict__ oA) {
    __shared__ _Float16 kk[8352];     // k: [line][key][96]; then out staging [line][l][104]
    __shared__ _Float16 vT[7744];     // plane lh=line*4+head, stride 968: [hd][40 keys]
    int t = threadIdx.x;
    int bid = blockIdx.x;
    int b = bid / 800;
    int r0 = (bid % 800) * 2;

    auto smap = [&](int r, int l) -> int {
        if (AXIS == 0) return l * 1600 + r;
        else if (AXIS == 1) { int d = r / 40, w = r % 40; return d * 1600 + l * 40 + w; }
        else return r * 40 + l;
    };
    const uint4* src = (const uint4*)qA;
    // stage k (channels 96..192): 2*40*12 uint4
    for (int i = t; i < 960; i += 320) {
        int line = i / 480, key = (i % 480) / 12, seg = i % 12;
        int row = b * 64000 + smap(r0 + line, key);
        ((uint4*)kk)[i] = src[(size_t)row * 36 + 12 + seg];
    }
    // stage v transposed (channels 192..288)
    for (int i = t; i < 960; i += 320) {
        int line = i / 480, key = (i % 480) / 12, seg = i % 12;
        int row = b * 64000 + smap(r0 + line, key);
        uint4 v = src[(size_t)row * 36 + 24 + seg];
        _Float16 tmp[8];
        *(uint4*)tmp = v;
#pragma unroll
        for (int e = 0; e < 8; e++) {
            int hdg = seg * 8 + e;
            vT[(line * 4 + hdg / 24) * 968 + (hdg % 24) * 40 + key] = tmp[e];
        }
    }

    int line = t / 160, head = (t % 160) / 40, ql = t % 40;
    int rr = r0 + line;
    // q (scaled+biased), gathered from global
    uint qu[12];
    {
        const uint4* qp = (const uint4*)(qA + ((size_t)(b * 64000 + smap(rr, ql))) * 288 + head * 24);
#pragma unroll
        for (int j = 0; j < 3; j++) *(uint4*)&qu[j * 4] = qp[j];
    }
    __syncthreads();

    float s[40];
    const uint4* kbase = (const uint4*)kk + line * 480 + head * 3;
#pragma unroll 4
    for (int key = 0; key < 40; key++) {
        uint kku[12];
#pragma unroll
        for (int j = 0; j < 3; j++) *(uint4*)&kku[j * 4] = kbase[key * 12 + j];
        float a = 0.f;
#pragma unroll
        for (int i = 0; i < 12; i++) a = fdot2(kku[i], qu[i], a);
        s[key] = a;
    }

    float mx = -1e30f;
#pragma unroll
    for (int i = 0; i < 40; i++) mx = fmaxf(mx, s[i]);
    float sum = 0.f;
#pragma unroll
    for (int i = 0; i < 40; i++) { s[i] = __expf(s[i] - mx); sum += s[i]; }
    float inv = 1.f / sum;

    uint pw[20];
#pragma unroll
    for (int i = 0; i < 20; i++) {
        half2 a = { (_Float16)(s[2 * i] * inv), (_Float16)(s[2 * i + 1] * inv) };
        pw[i] = __builtin_bit_cast(unsigned int, a);
    }

    __syncthreads();   // all score-reads of kk done; kk becomes output staging

    float o[24];
    const uint4* vbase = (const uint4*)vT + (line * 4 + head) * 121;
#pragma unroll 2
    for (int hd = 0; hd < 24; hd++) {
        uint vv[20];
#pragma unroll
        for (int j = 0; j < 5; j++) *(uint4*)&vv[j * 4] = vbase[hd * 5 + j];
        float a = 0.f;
#pragma unroll
        for (int i = 0; i < 20; i++) a = fdot2(vv[i], pw[i], a);
        o[hd] = a;
    }

    // stage into padded [line][l][104] layout (8-bank spread vs 2-bank unpadded)
    {
        _Float16 tm[24];
#pragma unroll
        for (int j = 0; j < 24; j++) tm[j] = (_Float16)o[j];
        _Float16* dA = &kk[(line * 40 + ql) * 104 + head * 24];
#pragma unroll
        for (int j = 0; j < 3; j++) ((uint4*)dA)[j] = ((uint4*)tm)[j];
    }
    __syncthreads();

    // contiguous flush: 80 rows x 96 f16 = 960 uint4
    uint4* dst = (uint4*)oA + ((size_t)(b * 64000 + r0 * 40)) * 12;
    for (int i = t; i < 960; i += 320) {
        int row = i / 12, seg = i % 12;
        dst[i] = *(const uint4*)&kk[row * 104 + seg * 8];
    }
}

// ---------------- proj GEMM with fused 3-axis sum ----------------
// out[b][c][s] = proj_w @ (o0[perm0(s)] + o1[perm1(s)] + o2[s]) + pb
__global__ __launch_bounds__(256) void k_proj(const _Float16* __restrict__ o0,
                                              const _Float16* __restrict__ o1,
                                              const _Float16* __restrict__ o2,
                                              const _Float16* __restrict__ wp,  // [96][96]
                                              const float* __restrict__ pb,
                                              float* __restrict__ out) {
    __shared__ _Float16 A[9216];
    __shared__ float bias_s[96];
    int t = threadIdx.x;
    int bid = blockIdx.x;
    int b = bid / 500;
    int s0 = (bid % 500) * 128;
    for (int i = t; i < 1152; i += 256) ((uint4*)A)[i] = ((const uint4*)wp)[i];
    if (t < 96) bias_s[t] = pb[t];
    __syncthreads();

    int ws = t >> 6, lane = t & 63;
    int n = lane & 31, kg = lane >> 5;
    int s = s0 + ws * 32 + n;

    int l0 = s / 1600, r0v = s % 1600;
    int row0 = r0v * 40 + l0;
    int d = s / 1600, rem = s % 1600, lh = rem / 40, wq2 = rem % 40;
    int row1 = (d * 40 + wq2) * 40 + lh;
    int row2 = s;

    const uint4* p0 = (const uint4*)(o0 + ((size_t)(b * 64000 + row0)) * 96);
    const uint4* p1 = (const uint4*)(o1 + ((size_t)(b * 64000 + row1)) * 96);
    const uint4* p2 = (const uint4*)(o2 + ((size_t)(b * 64000 + row2)) * 96);

    uint4 bf[3][6];
#pragma unroll
    for (int kc = 0; kc < 6; kc++) {
        bf[0][kc] = p0[kc * 2 + kg];
        bf[1][kc] = p1[kc * 2 + kg];
        bf[2][kc] = p2[kc * 2 + kg];
    }

    floatx16 acc[3];
#pragma unroll
    for (int mt = 0; mt < 3; mt++)
#pragma unroll
        for (int r = 0; r < 16; r++) acc[mt][r] = 0.f;

#pragma unroll
    for (int kc = 0; kc < 6; kc++) {
#pragma unroll
        for (int mt = 0; mt < 3; mt++) {
            uint4 au = *(const uint4*)&A[(mt * 32 + n) * 96 + kc * 16 + kg * 8];
            half8 ah = __builtin_bit_cast(half8, au);
            acc[mt] = __builtin_amdgcn_mfma_f32_32x32x16_f16(ah, __builtin_bit_cast(half8, bf[0][kc]), acc[mt], 0, 0, 0);
            acc[mt] = __builtin_amdgcn_mfma_f32_32x32x16_f16(ah, __builtin_bit_cast(half8, bf[1][kc]), acc[mt], 0, 0, 0);
            acc[mt] = __builtin_amdgcn_mfma_f32_32x32x16_f16(ah, __builtin_bit_cast(half8, bf[2][kc]), acc[mt], 0, 0, 0);
        }
    }

#pragma unroll
    for (int mt = 0; mt < 3; mt++)
#pragma unroll
        for (int r = 0; r < 16; r++) {
            int m = mt * 32 + (r & 3) + 8 * (r >> 2) + 4 * kg;
            out[((size_t)(b * 96 + m)) * 64000 + s] = acc[mt][r] + bias_s[m];
        }
}

extern "C" void kernel_launch(void* const* d_in, const int* in_sizes, int n_in,
                              void* d_out, int out_size, void* d_ws, size_t ws_size,
                              hipStream_t stream) {
    const float* x      = (const float*)d_in[0];
    const float* pos    = (const float*)d_in[1];
    const float* qkv_w  = (const float*)d_in[2];
    const float* qkv_b  = (const float*)d_in[3];
    const float* lp1_w  = (const float*)d_in[4];
    const float* lp1_b  = (const float*)d_in[5];
    const float* lp2_w  = (const float*)d_in[6];
    const float* lp2_b  = (const float*)d_in[7];
    const float* mod1_w = (const float*)d_in[8];
    const float* mod1_b = (const float*)d_in[9];
    const float* mod2_w = (const float*)d_in[10];
    const float* mod2_b = (const float*)d_in[11];
    // d_in[12..16]: pa_w, pa_b, R6_d, R6_h, R6_w — provably no-ops (see header)
    const float* proj_w = (const float*)d_in[17];
    const float* proj_b = (const float*)d_in[18];
    float* out = (float*)d_out;
    float* ws = (float*)d_ws;

    float* buf0 = ws;                          // 12,288,000 f32
    float* buf1 = ws + 12288000;               // 12,288,000 f32
    float2* stats = (float2*)(ws + 24576000);  // 192 float2
    unsigned short* wb2 = (unsigned short*)(ws + 24576384);   // 248,832 bf16
    _Float16* wq  = (_Float16*)(ws + 24700800);               // 27,648 f16
    _Float16* wpj = (_Float16*)(ws + 24714624);               // 9,216 f16
    _Float16* qA  = (_Float16*)(ws + 24720000);               // 36,864,000 f16
    unsigned short* in_t = (unsigned short*)buf1;             // bf16, dead after conv3
    _Float16* x_t = (_Float16*)buf0;                          // buf0 lower half (12.288M f16)
    _Float16* o2  = (_Float16*)(buf0 + 6144000);              // buf0 upper half
    _Float16* o0  = (_Float16*)buf1;                          // buf1 lower half
    _Float16* o1  = (_Float16*)buf1 + 12288000;               // buf1 upper half

    k_cvt_in<<<2000, 256, 0, stream>>>(pos, in_t);
    k_cvt_w<<<972, 256, 0, stream>>>(lp1_w, wb2);
    k_cvt_f16<<<108, 256, 0, stream>>>(qkv_w, wq, 27648);
    k_cvt_f16<<<36, 256, 0, stream>>>(proj_w, wpj, 9216);

    // local = conv1x1(gelu(IN(conv3(pos))))
    k_conv3_mfma<<<500, 256, 0, stream>>>(in_t, wb2, lp1_b, buf0);
    k_stats<<<192, 256, 0, stream>>>(buf0, stats);
    k_norm_gelu<<<12000, 256, 0, stream>>>(buf0, stats);
    k_conv1x1<0><<<2000, 256, 0, stream>>>(buf0, lp2_w, lp2_b, buf1);

    // mod = sigmoid(conv1x1(gelu(IN(conv1x1(local)))))
    k_conv1x1<0><<<2000, 256, 0, stream>>>(buf1, mod1_w, mod1_b, buf0);
    k_stats<<<192, 256, 0, stream>>>(buf0, stats);
    k_norm_gelu<<<12000, 256, 0, stream>>>(buf0, stats);
    k_conv1x1<1><<<2000, 256, 0, stream>>>(buf0, mod2_w, mod2_b, buf1);

    // x_mod (f16, [b][s][96]) into buf0 lower half
    k_xmod_t<<<2000, 256, 0, stream>>>(x, buf1, x_t);

    // qkv ONCE (s-order), then per-axis attention into per-axis o buffers
    k_qkv<<<1000, 256, 0, stream>>>(x_t, wq, qkv_b, qA);
    k_attn<0><<<1600, 320, 0, stream>>>(qA, o0);
    k_attn<1><<<1600, 320, 0, stream>>>(qA, o1);
    k_attn<2><<<1600, 320, 0, stream>>>(qA, o2);

    // out = proj(o0 + o1 + o2) with fused permuted gather
    k_proj<<<1000, 256, 0, stream>>>(o0, o1, o2, wpj, proj_b, out);
}

// Round 6
// 677.418 us; speedup vs baseline: 4.2244x; 1.1053x over previous
//
#include <hip/hip_runtime.h>

// Problem constants: B=2, C=96, D=H=W=40, S=64000, NH=4, HD=24, L=40
// Exact simplifications vs reference:
//  - pos_attn branch dropped (softmax row-shift invariance)
//  - R6 rotations dropped (R orthogonal; (Rq).(Rk) = q.k; v unrotated)
//  - mod1@ (lp2@B + b2) + b1 folded to W'@B + b'  (W' = mod1@lp2, exact)
// Round 6: f16 [b][s][96] middle pipeline. conv3 barrier-free (direct-global A
// fragments, L2-resident weights). IN stats via f16 stats kernel + atomics.
// Two MFMA GEMMs replace four fp32 conv1x1 passes; sigmoid*x fused in epilogue.
// Attention sums in place into one f16 osum buffer; proj is s-order GEMM.

typedef __attribute__((ext_vector_type(8))) _Float16 half8;
typedef __attribute__((ext_vector_type(2))) _Float16 half2;
typedef __attribute__((ext_vector_type(16))) float floatx16;

static __device__ __forceinline__ half2 h2(unsigned int u) {
    return __builtin_bit_cast(half2, u);
}
static __device__ __forceinline__ float fdot2(unsigned int a, unsigned int b, float c) {
    return __builtin_amdgcn_fdot2(h2(a), h2(b), c, false);
}

// ---------------- zero stats accumulators ----------------
__global__ void k_zero(float* __restrict__ p) {
    int t = threadIdx.x;
    for (int i = t; i < 768; i += 256) p[i] = 0.f;
}

// ---------------- prep: pos fp32 [b][c][s] -> f16 [b][s][c] ----------------
__global__ __launch_bounds__(256) void k_cvt_in(const float* __restrict__ pos,
                                                _Float16* __restrict__ in_t) {
    __shared__ _Float16 lds[64][97];
    int bid = blockIdx.x;
    int b = bid / 1000, s0 = (bid % 1000) * 64;
    int t = threadIdx.x;
    for (int i = t; i < 6144; i += 256) {
        int c = i / 64, sl = i % 64;
        lds[sl][c] = (_Float16)pos[(b * 96 + c) * 64000 + s0 + sl];
    }
    __syncthreads();
    _Float16* outp = in_t + ((size_t)b * 64000 + s0) * 96;
    for (int i = t; i < 6144; i += 256) {
        int sl = i / 96, c = i % 96;
        outp[i] = lds[sl][c];
    }
}

// ---------------- prep: lp1_w [o][c][tap] -> f16 wf [tap][o][c] ----------------
__global__ void k_cvt_w(const float* __restrict__ w, _Float16* __restrict__ wf) {
    int i = blockIdx.x * 256 + threadIdx.x;
    if (i < 248832) {
        int c = i % 96, m = (i / 96) % 96, tap = i / 9216;
        wf[i] = (_Float16)w[(m * 96 + c) * 27 + tap];
    }
}

// ---------------- prep: f32 -> f16 straight copy ----------------
__global__ void k_cvt_f16(const float* __restrict__ w, _Float16* __restrict__ o, int n) {
    int i = blockIdx.x * 256 + threadIdx.x;
    if (i < n) o[i] = (_Float16)w[i];
}

// ---------------- prep: W' = mod1_w @ lp2_w (f16), b' = mod1_w @ lp2_b + mod1_b ----------------
__global__ __launch_bounds__(256) void k_fold(const float* __restrict__ lp2_w,
                                              const float* __restrict__ lp2_b,
                                              const float* __restrict__ mod1_w,
                                              const float* __restrict__ mod1_b,
                                              _Float16* __restrict__ wfold,
                                              float* __restrict__ bfold) {
    int i = blockIdx.x * 256 + threadIdx.x;   // grid 36 -> 9216 outputs
    if (i < 9216) {
        int o = i / 96, c = i % 96;
        float a = 0.f;
        for (int k = 0; k < 96; k++) a += mod1_w[o * 96 + k] * lp2_w[k * 96 + c];
        wfold[i] = (_Float16)a;
    }
    if (blockIdx.x == 0 && threadIdx.x < 96) {
        int o = threadIdx.x;
        float a = mod1_b[o];
        for (int k = 0; k < 96; k++) a += mod1_w[o * 96 + k] * lp2_b[k];
        bfold[o] = a;
    }
}

// ---------------- conv 3x3x3 circular, barrier-free MFMA implicit GEMM ----------------
// A fragments read directly from global (weights L2-resident); no K-loop barriers.
// Output f16 [b][s][96] via padded LDS transpose (row stride 98 f16, conflict-free).
__global__ __launch_bounds__(256) void k_conv3_v2(const _Float16* __restrict__ in_t,
                                                  const _Float16* __restrict__ wf,  // [tap][m][c]
                                                  const float* __restrict__ bias,
                                                  _Float16* __restrict__ c3) {
    __shared__ int tbl[27 * 256];
    __shared__ _Float16 st[256 * 98];
    __shared__ float bsh[96];
    int t = threadIdx.x;
    int bid = blockIdx.x;
    int b = bid / 250;
    int s0 = (bid % 250) * 256;

    for (int u = t; u < 27 * 256; u += 256) {
        int tap = u >> 8, nl = u & 255;
        int kd = tap / 9, kh = (tap / 3) % 3, kw = tap % 3;
        int s = s0 + nl;
        int d = s / 1600, r = s - d * 1600;
        int h = r / 40, w = r - h * 40;
        int ds = d + kd - 1; if (ds < 0) ds += 40; else if (ds >= 40) ds -= 40;
        int hs = h + kh - 1; if (hs < 0) hs += 40; else if (hs >= 40) hs -= 40;
        int wv2 = w + kw - 1; if (wv2 < 0) wv2 += 40; else if (wv2 >= 40) wv2 -= 40;
        tbl[u] = ((ds * 1600 + hs * 40 + wv2) * 96) * 2;   // byte offset in batch slab
    }
    if (t < 96) bsh[t] = bias[t];
    __syncthreads();

    int wv = t >> 6, lane = t & 63;
    int n31 = lane & 31, kg = lane >> 5;
    const char* inb = (const char*)(in_t + (size_t)b * 64000 * 96) + kg * 16;

    floatx16 acc[3][2];
#pragma unroll
    for (int mt = 0; mt < 3; mt++)
#pragma unroll
        for (int nt = 0; nt < 2; nt++)
#pragma unroll
            for (int r = 0; r < 16; r++) acc[mt][nt][r] = 0.f;

    for (int tap = 0; tap < 27; tap++) {
        int ta0 = tbl[tap * 256 + wv * 64 + n31];
        int ta1 = tbl[tap * 256 + wv * 64 + 32 + n31];
        const char* pb0 = inb + ta0;
        const char* pb1 = inb + ta1;
        const _Float16* wt = wf + tap * 9216 + kg * 8;
#pragma unroll
        for (int j = 0; j < 6; j++) {
            half8 a0 = *(const half8*)(wt + (n31) * 96 + j * 16);
            half8 a1 = *(const half8*)(wt + (32 + n31) * 96 + j * 16);
            half8 a2 = *(const half8*)(wt + (64 + n31) * 96 + j * 16);
            half8 b0 = *(const half8*)(pb0 + j * 32);
            half8 b1 = *(const half8*)(pb1 + j * 32);
            acc[0][0] = __builtin_amdgcn_mfma_f32_32x32x16_f16(a0, b0, acc[0][0], 0, 0, 0);
            acc[0][1] = __builtin_amdgcn_mfma_f32_32x32x16_f16(a0, b1, acc[0][1], 0, 0, 0);
            acc[1][0] = __builtin_amdgcn_mfma_f32_32x32x16_f16(a1, b0, acc[1][0], 0, 0, 0);
            acc[1][1] = __builtin_amdgcn_mfma_f32_32x32x16_f16(a1, b1, acc[1][1], 0, 0, 0);
            acc[2][0] = __builtin_amdgcn_mfma_f32_32x32x16_f16(a2, b0, acc[2][0], 0, 0, 0);
            acc[2][1] = __builtin_amdgcn_mfma_f32_32x32x16_f16(a2, b1, acc[2][1], 0, 0, 0);
        }
    }

#pragma unroll
    for (int mt = 0; mt < 3; mt++)
#pragma unroll
        for (int nt = 0; nt < 2; nt++)
#pragma unroll
            for (int r = 0; r < 16; r++) {
                int m = mt * 32 + (r & 3) + 8 * (r >> 2) + 4 * kg;
                int sl = wv * 64 + nt * 32 + n31;
                st[sl * 98 + m] = (_Float16)(acc[mt][nt][r] + bsh[m]);
            }
    __syncthreads();

    unsigned int* dst = (unsigned int*)(c3 + ((size_t)(b * 64000 + s0)) * 96);
    for (int i = t; i < 12288; i += 256) {
        int row = i / 48, sg = i % 48;
        dst[i] = *(const unsigned int*)&st[row * 98 + sg * 2];
    }
}

// ---------------- per-(b,c) stats over f16 [b][s][96]: atomic partial sums ----------------
__global__ __launch_bounds__(192) void k_stats_sc(const _Float16* __restrict__ in,
                                                  float* __restrict__ raw) {   // [192][2]
    __shared__ float red_s[16][96], red_q[16][96];
    int bid = blockIdx.x;            // 100 blocks: b = bid/50, chunk of 1280 s
    int b = bid / 50, ch = bid % 50;
    int t = threadIdx.x;
    int sp = t / 12, cs = t % 12;
    const uint4* base = (const uint4*)(in + ((size_t)(b * 64000 + ch * 1280)) * 96);
    float s8[8], q8[8];
#pragma unroll
    for (int e = 0; e < 8; e++) { s8[e] = 0.f; q8[e] = 0.f; }
    for (int i = 0; i < 80; i++) {
        uint4 v = base[(sp + i * 16) * 12 + cs];
        half8 h = __builtin_bit_cast(half8, v);
#pragma unroll
        for (int e = 0; e < 8; e++) { float f = (float)h[e]; s8[e] += f; q8[e] += f * f; }
    }
#pragma unroll
    for (int e = 0; e < 8; e++) { red_s[sp][cs * 8 + e] = s8[e]; red_q[sp][cs * 8 + e] = q8[e]; }
    __syncthreads();
    if (t < 96) {
        float S = 0.f, Q = 0.f;
        for (int k = 0; k < 16; k++) { S += red_s[k][t]; Q += red_q[k][t]; }
        atomicAdd(&raw[(b * 96 + t) * 2], S);
        atomicAdd(&raw[(b * 96 + t) * 2 + 1], Q);
    }
}

// ---------------- finalize stats: (sum, sumsq) -> (mu, rstd) ----------------
__global__ void k_finalize(const float* __restrict__ raw, float2* __restrict__ sf) {
    int t = threadIdx.x;
    if (t < 192) {
        float S = raw[t * 2], Q = raw[t * 2 + 1];
        float mu = S * (1.f / 64000.f);
        float var = Q * (1.f / 64000.f) - mu * mu;
        sf[t] = make_float2(mu, rsqrtf(var + 1e-5f));
    }
}

// ---------------- norm + exact gelu on f16 [b][s][96], in-place ----------------
__global__ __launch_bounds__(256) void k_ng16(_Float16* __restrict__ x, const float2* __restrict__ sf) {
    int t = threadIdx.x, bid = blockIdx.x;
    uint4* p = (uint4*)x;
#pragma unroll
    for (int k = 0; k < 4; k++) {
        int i = bid * 1024 + k * 256 + t;      // uint4 index, 1,536,000 total
        int e0 = i * 8;
        int b = e0 / 6144000;
        int c0 = e0 % 96;
        const float2* sp = &sf[b * 96 + c0];
        uint4 v = p[i];
        half8 h = __builtin_bit_cast(half8, v);
        _Float16 o[8];
#pragma unroll
        for (int e = 0; e < 8; e++) {
            float2 st = sp[e];
            float u = ((float)h[e] - st.x) * st.y;
            o[e] = (_Float16)(0.5f * u * (1.f + erff(u * 0.70710678118654752f)));
        }
        p[i] = *(uint4*)o;
    }
}

// ---------------- 96x96 f16 MFMA GEMM on [b][s][96]; MODE 1: sigmoid * x epilogue ----------------
template <int MODE>
__global__ __launch_bounds__(256) void k_gemm96(const _Float16* __restrict__ in,
                                                const _Float16* __restrict__ w,   // [96][96]
                                                const float* __restrict__ bias,
                                                const float* __restrict__ xg,     // [b][c][s] f32 (MODE 1)
                                                _Float16* __restrict__ outp) {
    __shared__ _Float16 un[12544];   // union: W (9216) | out staging 128 x 98
    __shared__ float bias_s[96];
    int t = threadIdx.x, bid = blockIdx.x;
    int b = bid / 500, s0 = (bid % 500) * 128;
    for (int i = t; i < 1152; i += 256) ((uint4*)un)[i] = ((const uint4*)w)[i];
    if (t < 96) bias_s[t] = bias[t];
    __syncthreads();

    int ws = t >> 6, lane = t & 63;
    int n = lane & 31, kg = lane >> 5;
    int p = ws * 32 + n;
    const uint4* brow = (const uint4*)(in + ((size_t)(b * 64000 + s0 + p)) * 96);
    uint4 bf[6];
#pragma unroll
    for (int kc = 0; kc < 6; kc++) bf[kc] = brow[kc * 2 + kg];

    floatx16 acc[3];
#pragma unroll
    for (int mt = 0; mt < 3; mt++)
#pragma unroll
        for (int r = 0; r < 16; r++) acc[mt][r] = 0.f;
#pragma unroll
    for (int kc = 0; kc < 6; kc++) {
        half8 bfh = __builtin_bit_cast(half8, bf[kc]);
#pragma unroll
        for (int mt = 0; mt < 3; mt++) {
            uint4 au = *(const uint4*)&un[(mt * 32 + n) * 96 + kc * 16 + kg * 8];
            acc[mt] = __builtin_amdgcn_mfma_f32_32x32x16_f16(__builtin_bit_cast(half8, au), bfh, acc[mt], 0, 0, 0);
        }
    }
    __syncthreads();   // done reading W; un becomes output staging

#pragma unroll
    for (int mt = 0; mt < 3; mt++)
#pragma unroll
        for (int r = 0; r < 16; r++) {
            int m = mt * 32 + (r & 3) + 8 * (r >> 2) + 4 * kg;
            int sl = ws * 32 + n;
            float v = acc[mt][r] + bias_s[m];
            if (MODE == 1) {
                v = 1.f / (1.f + __expf(-v));
                v *= xg[((size_t)(b * 96 + m)) * 64000 + s0 + sl];
            }
            un[sl * 98 + m] = (_Float16)v;
        }
    __syncthreads();

    unsigned int* dst = (unsigned int*)(outp + ((size_t)(b * 64000 + s0)) * 96);
    for (int i = t; i < 6144; i += 256) {
        int row = i / 48, sg = i % 48;
        dst[i] = *(const unsigned int*)&un[row * 98 + sg * 2];
    }
}

// ---------------- qkv GEMM (ONCE): qA[b][s][288] f16, natural s-order ----------------
__global__ __launch_bounds__(256) void k_qkv(const _Float16* __restrict__ xt,
                                             const _Float16* __restrict__ wq,  // [288][96]
                                             const float* __restrict__ qb,
                                             _Float16* __restrict__ qA) {
    __shared__ _Float16 smem[27648];   // union: A (288x96) then epi (64 x 296)
    __shared__ float bias_s[288];
    int t = threadIdx.x;
    int bid = blockIdx.x;
    int b = bid / 500;
    int s0 = (bid % 500) * 128;

    for (int i = t; i < 3456; i += 256) ((uint4*)smem)[i] = ((const uint4*)wq)[i];
    for (int i = t; i < 288; i += 256) bias_s[i] = qb[i];
    __syncthreads();

    int ws = t >> 6, lane = t & 63;
    int n = lane & 31, kg = lane >> 5;
    int p = ws * 32 + n;

    const uint4* brow = (const uint4*)(xt + ((size_t)(b * 64000 + s0 + p)) * 96);
    uint4 bf[6];
#pragma unroll
    for (int kc = 0; kc < 6; kc++) bf[kc] = brow[kc * 2 + kg];

    floatx16 acc[9];
#pragma unroll
    for (int mt = 0; mt < 9; mt++)
#pragma unroll
        for (int r = 0; r < 16; r++) acc[mt][r] = 0.f;

#pragma unroll
    for (int kc = 0; kc < 6; kc++) {
        half8 bfh = __builtin_bit_cast(half8, bf[kc]);
#pragma unroll
        for (int mt = 0; mt < 9; mt++) {
            uint4 au = *(const uint4*)&smem[(mt * 32 + n) * 96 + kc * 16 + kg * 8];
            acc[mt] = __builtin_amdgcn_mfma_f32_32x32x16_f16(__builtin_bit_cast(half8, au), bfh, acc[mt], 0, 0, 0);
        }
    }

    const float scale = 0.20412414523193154f;
    for (int q = 0; q < 2; q++) {
        __syncthreads();
        if ((ws >> 1) == q) {
            int pl = (ws & 1) * 32 + n;
#pragma unroll
            for (int mt = 0; mt < 9; mt++)
#pragma unroll
                for (int g = 0; g < 4; g++) {
                    int m0 = mt * 32 + g * 8 + kg * 4;
                    _Float16 tm[4];
#pragma unroll
                    for (int j = 0; j < 4; j++) {
                        float v = acc[mt][g * 4 + j] + bias_s[m0 + j];
                        if (m0 + j < 96) v *= scale;
                        tm[j] = (_Float16)v;
                    }
                    *(uint2*)&smem[pl * 296 + m0] = *(uint2*)tm;
                }
        }
        __syncthreads();
        for (int idx = t; idx < 2304; idx += 256) {
            int pl = idx / 36, seg = idx % 36;
            int s = s0 + q * 64 + pl;
            uint4 v = *(const uint4*)&smem[pl * 296 + seg * 8];
            *(uint4*)&qA[((size_t)(b * 64000 + s)) * 288 + seg * 8] = v;
        }
    }
}

// ---------------- fused axial attention: softmax + PV, sum into osum[b][s][96] ----------------
// block=320: 2 lines x (4 heads x 40 queries), one query/thread. launch_bounds(320,3): no spills.
template <int AXIS, bool ACC>
__global__ __launch_bounds__(320, 3) void k_attn(const _Float16* __restrict__ qA,
                                                 _Float16* __restrict__ osum) {
    __shared__ _Float16 kk[8352];     // k: [line][key][96]; then out staging [line][l][104]
    __shared__ _Float16 vT[7744];     // plane lh=line*4+head, stride 968: [hd][40 keys]
    int t = threadIdx.x;
    int bid = blockIdx.x;
    int b = bid / 800;
    int r0 = (bid % 800) * 2;

    auto smap = [&](int r, int l) -> int {
        if (AXIS == 0) return l * 1600 + r;
        else if (AXIS == 1) { int d = r / 40, w = r % 40; return d * 1600 + l * 40 + w; }
        else return r * 40 + l;
    };
    const uint4* src = (const uint4*)qA;
    for (int i = t; i < 960; i += 320) {
        int line = i / 480, key = (i % 480) / 12, seg = i % 12;
        int row = b * 64000 + smap(r0 + line, key);
        ((uint4*)kk)[i] = src[(size_t)row * 36 + 12 + seg];
    }
    for (int i = t; i < 960; i += 320) {
        int line = i / 480, key = (i % 480) / 12, seg = i % 12;
        int row = b * 64000 + smap(r0 + line, key);
        uint4 v = src[(size_t)row * 36 + 24 + seg];
        _Float16 tmp[8];
        *(uint4*)tmp = v;
#pragma unroll
        for (int e = 0; e < 8; e++) {
            int hdg = seg * 8 + e;
            vT[(line * 4 + hdg / 24) * 968 + (hdg % 24) * 40 + key] = tmp[e];
        }
    }

    int line = t / 160, head = (t % 160) / 40, ql = t % 40;
    int rr = r0 + line;
    unsigned int qu[12];
    {
        const uint4* qp = (const uint4*)(qA + ((size_t)(b * 64000 + smap(rr, ql))) * 288 + head * 24);
#pragma unroll
        for (int j = 0; j < 3; j++) *(uint4*)&qu[j * 4] = qp[j];
    }
    __syncthreads();

    float s[40];
    const uint4* kbase = (const uint4*)kk + line * 480 + head * 3;
#pragma unroll 4
    for (int key = 0; key < 40; key++) {
        unsigned int kku[12];
#pragma unroll
        for (int j = 0; j < 3; j++) *(uint4*)&kku[j * 4] = kbase[key * 12 + j];
        float a = 0.f;
#pragma unroll
        for (int i = 0; i < 12; i++) a = fdot2(kku[i], qu[i], a);
        s[key] = a;
    }

    float mx = -1e30f;
#pragma unroll
    for (int i = 0; i < 40; i++) mx = fmaxf(mx, s[i]);
    float sum = 0.f;
#pragma unroll
    for (int i = 0; i < 40; i++) { s[i] = __expf(s[i] - mx); sum += s[i]; }
    float inv = 1.f / sum;

    unsigned int pw[20];
#pragma unroll
    for (int i = 0; i < 20; i++) {
        half2 a = { (_Float16)(s[2 * i] * inv), (_Float16)(s[2 * i + 1] * inv) };
        pw[i] = __builtin_bit_cast(unsigned int, a);
    }

    __syncthreads();   // kk becomes output staging

    float o[24];
    const uint4* vbase = (const uint4*)vT + (line * 4 + head) * 121;
#pragma unroll 2
    for (int hd = 0; hd < 24; hd++) {
        unsigned int vv[20];
#pragma unroll
        for (int j = 0; j < 5; j++) *(uint4*)&vv[j * 4] = vbase[hd * 5 + j];
        float a = 0.f;
#pragma unroll
        for (int i = 0; i < 20; i++) a = fdot2(vv[i], pw[i], a);
        o[hd] = a;
    }

    {
        _Float16 tm[24];
#pragma unroll
        for (int j = 0; j < 24; j++) tm[j] = (_Float16)o[j];
        _Float16* dA = &kk[(line * 40 + ql) * 104 + head * 24];
#pragma unroll
        for (int j = 0; j < 3; j++) ((uint4*)dA)[j] = ((uint4*)tm)[j];
    }
    __syncthreads();

    // flush 80 rows x 96 f16 to osum[smap(r,l)] (192B rows; contiguous for AXIS 2)
    uint4* dst = (uint4*)osum;
    for (int i = t; i < 960; i += 320) {
        int row = i / 12, seg = i % 12;
        int s2 = smap(r0 + row / 40, row % 40);
        size_t di = ((size_t)(b * 64000 + s2)) * 12 + seg;
        uint4 v = *(const uint4*)&kk[row * 104 + seg * 8];
        if (ACC) {
            half8 a = __builtin_bit_cast(half8, dst[di]);
            half8 c = __builtin_bit_cast(half8, v);
            dst[di] = __builtin_bit_cast(uint4, a + c);
        } else {
            dst[di] = v;
        }
    }
}

// ---------------- proj GEMM: out[b][c][s] = proj_w @ osum[b][s][96] + pb ----------------
__global__ __launch_bounds__(256) void k_proj(const _Float16* __restrict__ osum,
                                              const _Float16* __restrict__ wp,  // [96][96]
                                              const float* __restrict__ pb,
                                              float* __restrict__ out) {
    __shared__ _Float16 A[9216];
    __shared__ float bias_s[96];
    int t = threadIdx.x;
    int bid = blockIdx.x;
    int b = bid / 500;
    int s0 = (bid % 500) * 128;
    for (int i = t; i < 1152; i += 256) ((uint4*)A)[i] = ((const uint4*)wp)[i];
    if (t < 96) bias_s[t] = pb[t];
    __syncthreads();

    int ws = t >> 6, lane = t & 63;
    int n = lane & 31, kg = lane >> 5;
    int s = s0 + ws * 32 + n;

    const uint4* brow = (const uint4*)(osum + ((size_t)(b * 64000 + s0 + ws * 32 + n)) * 96);
    uint4 bf[6];
#pragma unroll
    for (int kc = 0; kc < 6; kc++) bf[kc] = brow[kc * 2 + kg];

    floatx16 acc[3];
#pragma unroll
    for (int mt = 0; mt < 3; mt++)
#pragma unroll
        for (int r = 0; r < 16; r++) acc[mt][r] = 0.f;

#pragma unroll
    for (int kc = 0; kc < 6; kc++) {
        half8 bfh = __builtin_bit_cast(half8, bf[kc]);
#pragma unroll
        for (int mt = 0; mt < 3; mt++) {
            uint4 au = *(const uint4*)&A[(mt * 32 + n) * 96 + kc * 16 + kg * 8];
            acc[mt] = __builtin_amdgcn_mfma_f32_32x32x16_f16(__builtin_bit_cast(half8, au), bfh, acc[mt], 0, 0, 0);
        }
    }

#pragma unroll
    for (int mt = 0; mt < 3; mt++)
#pragma unroll
        for (int r = 0; r < 16; r++) {
            int m = mt * 32 + (r & 3) + 8 * (r >> 2) + 4 * kg;
            out[((size_t)(b * 96 + m)) * 64000 + s] = acc[mt][r] + bias_s[m];
        }
}

extern "C" void kernel_launch(void* const* d_in, const int* in_sizes, int n_in,
                              void* d_out, int out_size, void* d_ws, size_t ws_size,
                              hipStream_t stream) {
    const float* x      = (const float*)d_in[0];
    const float* pos    = (const float*)d_in[1];
    const float* qkv_w  = (const float*)d_in[2];
    const float* qkv_b  = (const float*)d_in[3];
    const float* lp1_w  = (const float*)d_in[4];
    const float* lp1_b  = (const float*)d_in[5];
    const float* lp2_w  = (const float*)d_in[6];
    const float* lp2_b  = (const float*)d_in[7];
    const float* mod1_w = (const float*)d_in[8];
    const float* mod1_b = (const float*)d_in[9];
    const float* mod2_w = (const float*)d_in[10];
    const float* mod2_b = (const float*)d_in[11];
    // d_in[12..16]: pa_w, pa_b, R6_d, R6_h, R6_w — provably no-ops (see header)
    const float* proj_w = (const float*)d_in[17];
    const float* proj_b = (const float*)d_in[18];
    float* out = (float*)d_out;
    float* ws = (float*)d_ws;

    // f16 buffers (sizes in f32-float units of ws):
    _Float16* bufA = (_Float16*)ws;                        // 12.288M f16: c3/B0 -> xm
    _Float16* bufB = (_Float16*)(ws + 6144000);            // 12.288M f16: C2/D -> osum
    _Float16* qA   = (_Float16*)(ws + 12288000);           // 36.864M f16
    _Float16* in_t = qA;                                   // pos f16 [s][c], dead before qkv
    _Float16* wf   = (_Float16*)(ws + 30720000);           // 248,832 f16
    _Float16* wq   = (_Float16*)(ws + 30844416);           // 27,648 f16
    _Float16* wpj  = (_Float16*)(ws + 30858240);           // 9,216 f16
    _Float16* wfold= (_Float16*)(ws + 30862848);           // 9,216 f16
    _Float16* wm2  = (_Float16*)(ws + 30867456);           // 9,216 f16
    float* bfold   = ws + 30872064;                        // 96 f32
    float* raw     = ws + 30872160;                        // 768 f32 (raw0 | raw1)
    float2* sf0    = (float2*)(ws + 30872928);             // 192 float2
    float2* sf1    = (float2*)(ws + 30873312);             // 192 float2
    float* raw0 = raw, *raw1 = raw + 384;

    k_zero<<<1, 256, 0, stream>>>(raw);
    k_cvt_in<<<2000, 256, 0, stream>>>(pos, in_t);
    k_cvt_w<<<972, 256, 0, stream>>>(lp1_w, wf);
    k_fold<<<36, 256, 0, stream>>>(lp2_w, lp2_b, mod1_w, mod1_b, wfold, bfold);
    k_cvt_f16<<<36, 256, 0, stream>>>(mod2_w, wm2, 9216);
    k_cvt_f16<<<108, 256, 0, stream>>>(qkv_w, wq, 27648);
    k_cvt_f16<<<36, 256, 0, stream>>>(proj_w, wpj, 9216);

    // c3 = conv3(pos)  [f16, [b][s][96]]
    k_conv3_v2<<<500, 256, 0, stream>>>(in_t, wf, lp1_b, bufA);
    // B0 = gelu(IN(c3)) in-place
    k_stats_sc<<<100, 192, 0, stream>>>(bufA, raw0);
    k_finalize<<<1, 256, 0, stream>>>(raw0, sf0);
    k_ng16<<<1500, 256, 0, stream>>>(bufA, sf0);
    // C2 = W' @ B0 + b'   (folded lp2 -> mod1)
    k_gemm96<0><<<1000, 256, 0, stream>>>(bufA, wfold, bfold, nullptr, bufB);
    // D = gelu(IN(C2)) in-place
    k_stats_sc<<<100, 192, 0, stream>>>(bufB, raw1);
    k_finalize<<<1, 256, 0, stream>>>(raw1, sf1);
    k_ng16<<<1500, 256, 0, stream>>>(bufB, sf1);
    // xm = x * sigmoid(mod2 @ D + b)   [f16 [b][s][96], into bufA (B0 dead)]
    k_gemm96<1><<<1000, 256, 0, stream>>>(bufB, wm2, mod2_b, x, bufA);

    // qkv ONCE (s-order); qA overwrites in_t (dead)
    k_qkv<<<1000, 256, 0, stream>>>(bufA, wq, qkv_b, qA);
    // attention: axis 2 writes osum (contiguous), axes 0/1 accumulate (192B-row RMW)
    k_attn<2, false><<<1600, 320, 0, stream>>>(qA, bufB);
    k_attn<0, true ><<<1600, 320, 0, stream>>>(qA, bufB);
    k_attn<1, true ><<<1600, 320, 0, stream>>>(qA, bufB);

    // out = proj(osum)
    k_proj<<<1000, 256, 0, stream>>>(bufB, wpj, proj_b, out);
}